// Round 8
// baseline (114.471 us; speedup 1.0000x reference)
//
#include <hip/hip_runtime.h>
#include <math.h>

#define TAUF  1.0e-4f
#define LNEPS 1.0e-5f

typedef __bf16 bf16x8 __attribute__((ext_vector_type(8)));
typedef float  f32x4  __attribute__((ext_vector_type(4)));

union U4 { uint4 u4; unsigned short us[8]; bf16x8 bv; };

static __device__ __forceinline__ unsigned short f2bf(float f) {
    union { float f; unsigned u; } v; v.f = f;
    unsigned r = v.u + 0x7fffu + ((v.u >> 16) & 1u);
    return (unsigned short)(r >> 16);
}
static __device__ __forceinline__ float bf2f(unsigned short h) {
    union { unsigned u; float f; } v; v.u = ((unsigned)h) << 16;
    return v.f;
}

// ---------------- workspace layout (float offsets, all 16B-aligned) ----------------
static const unsigned CE_OFF   = 0u;         // 768
static const unsigned B0_OFF   = 768u;       // 256
static const unsigned C1_OFF   = 1024u;      // 256
static const unsigned R2_OFF   = 1280u;      // 16 (pad 16)
static const unsigned UF_OFF   = 1296u;      // 18*64 uint4 = 4608 f
static const unsigned B1F_OFF  = 5904u;      // 4*64 uint4  = 1024 f
static const unsigned GF_OFF   = 6928u;      // 18*64 uint4 = 4608 f
static const unsigned QT_OFF   = 11536u;     // 393216 bf16 = 196608 f
static const unsigned W1T_OFF  = 208144u;    // 262144 bf16 = 131072 f
static const unsigned W2T_OFF  = 339216u;    // 262144 bf16 = 131072 f
static const unsigned WS_FLOATS = 470288u;   // ~1.9 MB

// ================= prep: ALL x-independent prep in ONE launch =================
// b <  96 : Qt MFMA GEMM from f32 out_w / wv0_w / wein_w (2-stage LDS, 3 barriers)
// b < 352 : transpose ffn1_w -> w1t bf16
// b < 608 : transpose ffn2_w -> w2t bf16
// b < 612 : bias folds (ce, bias0)
// b = 612 : complex constants (C1, r2)
// b < 631 : ufrag (18) ; b < 635 : b1frag (4) ; b < 653 : gfrag (18)
__launch_bounds__(256)
__global__ void prep_k(const float* __restrict__ wv0_w, const float* __restrict__ wein_w,
                       const float* __restrict__ out_w,
                       const float* __restrict__ ffn1_w, const float* __restrict__ ffn2_w,
                       const float* __restrict__ wv0_b, const float* __restrict__ wein_b,
                       const float* __restrict__ out_b,
                       const float* __restrict__ B1g, const float* __restrict__ absB1,
                       const float* __restrict__ B2g,
                       unsigned short* __restrict__ Qt,
                       unsigned short* __restrict__ w1t, unsigned short* __restrict__ w2t,
                       float* __restrict__ ce, float* __restrict__ bias0,
                       float* __restrict__ C1, float* __restrict__ r2,
                       uint4* __restrict__ ufrag, uint4* __restrict__ b1frag,
                       uint4* __restrict__ gfrag)
{
    __shared__ float tile[32][33];
    __shared__ float sTf[128][68];
    int b = blockIdx.x, tid = threadIdx.x;
    if (b < 96) {
        int by = b >> 2, bx = b & 3;
        int row0 = by * 64, col0 = bx * 64;
        int z = row0 >> 8, o0 = row0 & 255;
        int s = (z < 3) ? z : z - 3;
        const float* Wsel = (z < 3) ? wv0_w : wein_w;
        int lane = tid & 63, w = tid >> 6;
        int rr = lane & 15, kq = lane >> 4;
        f32x4 acc[4];
        #pragma unroll
        for (int cg = 0; cg < 4; ++cg) acc[cg] = 0.f;
        for (int st = 0; st < 2; ++st) {
            #pragma unroll
            for (int i = 0; i < 8; ++i) {
                int idx = i*256 + tid;            // 2048 float4 slots
                int dd = idx >> 4, q = idx & 15;
                float4 v = *(const float4*)(out_w + (size_t)(z*256 + st*128 + dd)*256 + o0 + q*4);
                *(float4*)&sTf[dd][q*4] = v;
            }
            __syncthreads();
            for (int ks2 = 0; ks2 < 4; ++ks2) {
                int ks = st*4 + ks2;
                U4 av;
                #pragma unroll
                for (int j = 0; j < 8; ++j)
                    av.us[j] = f2bf(sTf[ks2*32 + kq*8 + j][w*16 + rr]);
                #pragma unroll
                for (int cg = 0; cg < 4; ++cg) {
                    const float* bp = Wsel + (size_t)(col0 + cg*16 + rr)*768 + s*256 + ks*32 + kq*8;
                    float4 b0 = *(const float4*)bp, b1 = *(const float4*)(bp + 4);
                    U4 bv;
                    bv.us[0]=f2bf(b0.x); bv.us[1]=f2bf(b0.y); bv.us[2]=f2bf(b0.z); bv.us[3]=f2bf(b0.w);
                    bv.us[4]=f2bf(b1.x); bv.us[5]=f2bf(b1.y); bv.us[6]=f2bf(b1.z); bv.us[7]=f2bf(b1.w);
                    acc[cg] = __builtin_amdgcn_mfma_f32_16x16x32_bf16(av.bv, bv.bv, acc[cg], 0, 0, 0);
                }
            }
            __syncthreads();
        }
        #pragma unroll
        for (int cg = 0; cg < 4; ++cg)
            #pragma unroll
            for (int e = 0; e < 4; ++e) {
                int row = row0 + w*16 + kq*4 + e;
                int col = col0 + cg*16 + rr;
                Qt[(size_t)row*256 + col] = f2bf(acc[cg][e]);
            }
    } else if (b < 352) {
        int bi = b - 96;
        int c0 = (bi & 31) * 32, r0 = (bi >> 5) * 32;
        int tx = tid & 31, ty = tid >> 5;
        #pragma unroll
        for (int i = 0; i < 4; ++i)
            tile[ty + i*8][tx] = ffn1_w[(size_t)(r0 + ty + i*8)*1024 + c0 + tx];
        __syncthreads();
        #pragma unroll
        for (int i = 0; i < 4; ++i)
            w1t[(size_t)(c0 + ty + i*8)*256 + r0 + tx] = f2bf(tile[tx][ty + i*8]);
    } else if (b < 608) {
        int bi = b - 352;
        int c0 = (bi & 7) * 32, r0 = (bi >> 3) * 32;
        int tx = tid & 31, ty = tid >> 5;
        #pragma unroll
        for (int i = 0; i < 4; ++i)
            tile[ty + i*8][tx] = ffn2_w[(size_t)(r0 + ty + i*8)*256 + c0 + tx];
        __syncthreads();
        #pragma unroll
        for (int i = 0; i < 4; ++i)
            w2t[(size_t)(c0 + ty + i*8)*1024 + r0 + tx] = f2bf(tile[tx][ty + i*8]);
    } else if (b < 612) {
        int which = b - 608;
        int o = tid;
        if (which == 3) {
            float acc = 0.f;
            for (int r = 0; r < 768; ++r) acc += wv0_b[r] * out_w[(size_t)r*256 + o];
            bias0[o] = out_b[o] + TAUF * acc;
        } else {
            float a2 = 0.f;
            for (int c = 0; c < 256; ++c)
                a2 += wein_b[which*256 + c] * out_w[(size_t)(768 + which*256 + c)*256 + o];
            ce[which*256 + o] = a2;
        }
    } else if (b == 612) {
        int p = tid >> 4, q = tid & 15;
        float c1 = 0.f;
        for (int e = 0; e < 120; ++e) c1 += absB1[p*120+e] * absB1[q*120+e];
        C1[tid] = c1;
        if (tid < 16) {
            float bb = 0.f;
            for (int e = 0; e < 120; ++e) bb += absB1[tid*120+e];
            r2[tid] = bb;
        }
    } else {
        if (tid < 64) {
            int lane = tid, col = lane & 15, kq = lane >> 4;
            int fb = b - 613;
            U4 o;
            if (fb < 18) {                       // ufrag: U (t<560) / C0 ext
                int kt = fb;
                #pragma unroll
                for (int j = 0; j < 8; ++j) {
                    int t = kt*32 + kq*8 + j;
                    float v = 0.f;
                    if (t < 560) {
                        for (int e = 0; e < 120; ++e) v += absB1[col*120+e] * B2g[e*560+t];
                    } else {
                        int p = t - 560;
                        for (int e = 0; e < 120; ++e) v += absB1[col*120+e] * B1g[p*120+e];
                    }
                    o.us[j] = f2bf(v);
                }
                ufrag[kt*64 + lane] = o.u4;
            } else if (fb < 22) {                // b1frag
                int kt = fb - 18;
                #pragma unroll
                for (int j = 0; j < 8; ++j) {
                    int e = kt*32 + kq*8 + j;
                    o.us[j] = f2bf((e < 120) ? B1g[col*120 + e] : 0.f);
                }
                b1frag[kt*64 + lane] = o.u4;
            } else {                             // gfrag: sig*U (t<560) / C0*r1 ext
                int kt = fb - 22;
                #pragma unroll
                for (int j = 0; j < 8; ++j) {
                    int t = kt*32 + kq*8 + j;
                    float g;
                    if (t < 560) {
                        float u = 0.f, sgv = 0.f;
                        for (int e = 0; e < 120; ++e) {
                            float bv = B2g[e*560+t];
                            u += absB1[col*120+e] * bv;
                            sgv += bv;
                        }
                        g = sgv * u;
                    } else {
                        int p = t - 560;
                        float c0 = 0.f, r1v = 0.f;
                        for (int e = 0; e < 120; ++e) {
                            float bv = B1g[p*120+e];
                            c0 += absB1[col*120+e] * bv;
                            r1v += bv;
                        }
                        g = c0 * r1v;
                    }
                    o.us[j] = f2bf(g);
                }
                gfrag[kt*64 + lane] = o.u4;
            }
        }
    }
}

// ============== k_mega: 1024 threads; geo phases on partial waves, idle waves run Y-tiles ==============
__launch_bounds__(1024)
__global__ void k_mega(const float* __restrict__ x, const float* __restrict__ mask,
                       const int* __restrict__ e_i, const int* __restrict__ e_j,
                       const int* __restrict__ t_ij, const int* __restrict__ t_jk,
                       const int* __restrict__ t_ik,
                       const float* __restrict__ geom_w, const float* __restrict__ geom_b,
                       const float* __restrict__ log_sc,
                       const float* __restrict__ n1_g, const float* __restrict__ n1_b,
                       const float* __restrict__ n2g, const float* __restrict__ n2b,
                       const float* __restrict__ C1, const float* __restrict__ r2,
                       const uint4* __restrict__ ufrag, const uint4* __restrict__ b1frag,
                       const uint4* __restrict__ gfrag,
                       const unsigned short* __restrict__ Qt,
                       const float* __restrict__ bias0, const float* __restrict__ ce,
                       const unsigned short* __restrict__ w1t, const float* __restrict__ f1b,
                       const unsigned short* __restrict__ w2t, const float* __restrict__ f2b,
                       float* __restrict__ outp)
{
    __shared__ float sFbuf[16][264];           // xn (A,B), then x2 (F2..I)
    __shared__ unsigned short sNB[16*256];     // bf16 xn chunks (A..F), then x2n chunks (G,H)
    __shared__ unsigned short sY[16*1544];     // full Y [16][1536+8]
    __shared__ unsigned short sH[16*1024];     // h, frag layout
    __shared__ float sP[16][17];
    __shared__ float sW1e[3][128];
    __shared__ float sW2e[3][576];
    __shared__ float sMask[16];
    __shared__ float sO[6*256];
    __shared__ float sRsA[48];

    const int bb = blockIdx.x, tid = threadIdx.x;
    const int w = tid >> 6, lane = tid & 63;
    const int rr = lane & 15, kq = lane >> 4;

    // Y-tile helper: compute n16-tiles [nt0, nt0+cnt) of Y = xn @ Qt^T, reg-double-buffered
    auto y_run = [&](int nt0, int cnt) {
        U4 qf[8], qn[8];
        #pragma unroll
        for (int kt = 0; kt < 8; ++kt)
            qf[kt].u4 = *(const uint4*)(Qt + (size_t)(nt0*16 + rr)*256 + kt*32 + kq*8);
        for (int j = 0; j < cnt; ++j) {
            if (j + 1 < cnt) {
                #pragma unroll
                for (int kt = 0; kt < 8; ++kt)
                    qn[kt].u4 = *(const uint4*)(Qt + (size_t)((nt0+j+1)*16 + rr)*256 + kt*32 + kq*8);
            }
            f32x4 ya = {0.f, 0.f, 0.f, 0.f};
            #pragma unroll
            for (int kt = 0; kt < 8; ++kt) {
                int kg = kt*4 + kq;
                int swz = (kg & 24) | ((kg & 7) ^ (rr & 7));
                bf16x8 af = *(const bf16x8*)&sNB[rr*256 + swz*8];
                ya = __builtin_amdgcn_mfma_f32_16x16x32_bf16(af, qf[kt].bv, ya, 0, 0, 0);
            }
            #pragma unroll
            for (int e = 0; e < 4; ++e)
                sY[(kq*4 + e)*1544 + (nt0+j)*16 + rr] = f2bf(ya[e]);
            #pragma unroll
            for (int kt = 0; kt < 8; ++kt) qf[kt] = qn[kt];
        }
    };

    // ---- A. LayerNorm 1: wave w = row w (all 16 waves) ----
    {
        const int r = w, q = lane;
        const float* row = x + ((size_t)bb*16 + r)*256 + q*4;
        float4 va = *(const float4*)row;
        float v[4] = {va.x, va.y, va.z, va.w};
        float sum = v[0]+v[1]+v[2]+v[3];
        float ss  = v[0]*v[0]+v[1]*v[1]+v[2]*v[2]+v[3]*v[3];
        #pragma unroll
        for (int o = 32; o; o >>= 1) { sum += __shfl_xor(sum, o); ss += __shfl_xor(ss, o); }
        float mean = sum * (1.f/256.f);
        float rstd = rsqrtf(ss*(1.f/256.f) - mean*mean + LNEPS);
        ushort4 pk;
        float xv0 = (v[0]-mean)*rstd*n1_g[q*4+0] + n1_b[q*4+0];
        float xv1 = (v[1]-mean)*rstd*n1_g[q*4+1] + n1_b[q*4+1];
        float xv2 = (v[2]-mean)*rstd*n1_g[q*4+2] + n1_b[q*4+2];
        float xv3 = (v[3]-mean)*rstd*n1_g[q*4+3] + n1_b[q*4+3];
        sFbuf[r][q*4+0] = xv0; sFbuf[r][q*4+1] = xv1;
        sFbuf[r][q*4+2] = xv2; sFbuf[r][q*4+3] = xv3;
        pk.x = f2bf(xv0); pk.y = f2bf(xv1); pk.z = f2bf(xv2); pk.w = f2bf(xv3);
        int kg = q >> 1;
        int swz = (kg & 24) | ((kg & 7) ^ (r & 7));
        *(ushort4*)&sNB[r*256 + swz*8 + (q & 1)*4] = pk;
        if (tid < 16) sMask[tid] = mask[bb*16 + tid];
    }
    __syncthreads();

    // ---- B. P (waves 0-7) | Y tiles 0..15 (waves 8-15) ----
    if (w < 8) {
        int r = tid >> 5, g = (tid >> 1) & 15, half = tid & 1;
        int cb = half * 128;
        float a0 = 0.f, a1 = 0.f, a2 = 0.f, a3 = 0.f;
        for (int c = 0; c < 128; c += 4) {
            a0 += sFbuf[r][cb+c+0] * geom_w[(cb+c+0)*16 + g];
            a1 += sFbuf[r][cb+c+1] * geom_w[(cb+c+1)*16 + g];
            a2 += sFbuf[r][cb+c+2] * geom_w[(cb+c+2)*16 + g];
            a3 += sFbuf[r][cb+c+3] * geom_w[(cb+c+3)*16 + g];
        }
        float p = (a0+a1) + (a2+a3);
        p += __shfl_xor(p, 1);
        if (!half) sP[r][g] = p + geom_b[g];
    } else y_run((w-8)*2, 2);
    __syncthreads();

    // ---- C. W1 (waves 0-7) | Y tiles 16..31 (waves 8-15) ----
    if (w < 8) {
        int e = tid >> 2, s = tid & 3;
        if (e < 120 && s < 3) {
            int i0 = e_i[e], j0 = e_j[e];
            float d2 = 0.f;
            #pragma unroll
            for (int m = 0; m < 16; ++m) { float dd = sP[i0][m] - sP[j0][m]; d2 += dd*dd; }
            float mm = sMask[i0]*sMask[j0];
            d2 *= mm*mm;
            float sc = expf(log_sc[s]);
            sW1e[s][e] = expf(-d2/(2.f*sc*sc + 1e-8f)) * mm;
        }
        if (tid < 24) sW1e[tid >> 3][120 + (tid & 7)] = 0.f;
    } else y_run(16 + (w-8)*2, 2);
    __syncthreads();

    // ---- D. W2 + mask ext (waves 0-8) | Y tiles 32..45 (waves 9-15) ----
    if (w < 9) {
        if (tid < 560) {
            int t = tid;
            int a = t_ij[t], b2 = t_jk[t], c2 = t_ik[t];
            #pragma unroll
            for (int s = 0; s < 3; ++s) sW2e[s][t] = sW1e[s][a]*sW1e[s][b2]*sW1e[s][c2];
        } else if (tid < 576) {
            int p = tid - 560;
            float mv = sMask[p];
            #pragma unroll
            for (int s = 0; s < 3; ++s) sW2e[s][560 + p] = mv;
        }
    } else y_run(32 + (w-9)*2, 2);
    __syncthreads();

    // ---- E. edge-O (w0-2), node-O (w3), rsA-MFMA (w4) | Y tiles 46..78 (w5-15) ----
    if (w < 3) {
        int s = w;
        f32x4 acc = {0.f, 0.f, 0.f, 0.f};
        for (int kt = 0; kt < 18; ++kt) {
            U4 ub; ub.u4 = ufrag[kt*64 + lane];
            const float4* w4 = (const float4*)&sW2e[s][kt*32 + kq*8];
            float4 wa = w4[0], wb = w4[1];
            U4 av;
            av.us[0] = f2bf(wa.x * bf2f(ub.us[0]));
            av.us[1] = f2bf(wa.y * bf2f(ub.us[1]));
            av.us[2] = f2bf(wa.z * bf2f(ub.us[2]));
            av.us[3] = f2bf(wa.w * bf2f(ub.us[3]));
            av.us[4] = f2bf(wb.x * bf2f(ub.us[4]));
            av.us[5] = f2bf(wb.y * bf2f(ub.us[5]));
            av.us[6] = f2bf(wb.z * bf2f(ub.us[6]));
            av.us[7] = f2bf(wb.w * bf2f(ub.us[7]));
            acc = __builtin_amdgcn_mfma_f32_16x16x32_bf16(av.bv, ub.bv, acc, 0, 0, 0);
        }
        #pragma unroll
        for (int e = 0; e < 4; ++e) {
            int row = kq*4 + e;
            sO[(3+s)*256 + row*16 + rr] = acc[e] + TAUF*C1[row*16 + rr];
        }
    } else if (w == 3) {
        f32x4 acc3[3];
        acc3[0] = 0.f; acc3[1] = 0.f; acc3[2] = 0.f;
        for (int kt = 0; kt < 4; ++kt) {
            U4 ub; ub.u4 = b1frag[kt*64 + lane];
            float uf[8];
            #pragma unroll
            for (int j = 0; j < 8; ++j) uf[j] = bf2f(ub.us[j]);
            #pragma unroll
            for (int s = 0; s < 3; ++s) {
                const float4* w4 = (const float4*)&sW1e[s][kt*32 + kq*8];
                float4 wa = w4[0], wb = w4[1];
                U4 av;
                av.us[0] = f2bf(wa.x * uf[0]);
                av.us[1] = f2bf(wa.y * uf[1]);
                av.us[2] = f2bf(wa.z * uf[2]);
                av.us[3] = f2bf(wa.w * uf[3]);
                av.us[4] = f2bf(wb.x * uf[4]);
                av.us[5] = f2bf(wb.y * uf[5]);
                av.us[6] = f2bf(wb.z * uf[6]);
                av.us[7] = f2bf(wb.w * uf[7]);
                acc3[s] = __builtin_amdgcn_mfma_f32_16x16x32_bf16(av.bv, ub.bv, acc3[s], 0, 0, 0);
            }
        }
        #pragma unroll
        for (int s = 0; s < 3; ++s)
            #pragma unroll
            for (int e = 0; e < 4; ++e) {
                int row = kq*4 + e;
                sO[s*256 + row*16 + rr] = acc3[s][e] + ((row == rr) ? TAUF : 0.f);
            }
    } else if (w == 4) {
        // rsA[s][k] = sum_t' W2e[s][t'] * G[k][t']  (A row=s, B col=k), + TAU*r2[k]
        f32x4 acc = {0.f, 0.f, 0.f, 0.f};
        int srow = (rr < 3) ? rr : 0;
        for (int kt = 0; kt < 18; ++kt) {
            U4 gb; gb.u4 = gfrag[kt*64 + lane];
            const float4* w4 = (const float4*)&sW2e[srow][kt*32 + kq*8];
            float4 wa = w4[0], wb = w4[1];
            U4 av;
            av.us[0] = f2bf(wa.x); av.us[1] = f2bf(wa.y);
            av.us[2] = f2bf(wa.z); av.us[3] = f2bf(wa.w);
            av.us[4] = f2bf(wb.x); av.us[5] = f2bf(wb.y);
            av.us[6] = f2bf(wb.z); av.us[7] = f2bf(wb.w);
            acc = __builtin_amdgcn_mfma_f32_16x16x32_bf16(av.bv, gb.bv, acc, 0, 0, 0);
        }
        if (kq == 0) {
            #pragma unroll
            for (int e = 0; e < 3; ++e)
                sRsA[e*16 + rr] = acc[e] + TAUF * r2[rr];
        }
    } else y_run(46 + (w-5)*3, 3);
    __syncthreads();

    // ---- F1. leftover Y tiles 79..95 (1/wave + extra on wave 15); prefetch residual ----
    const int o = tid & 255, kh = tid >> 8;
    y_run(79 + w, 1);
    if (w == 15) y_run(95, 1);
    float xr[4];
    #pragma unroll
    for (int i = 0; i < 4; ++i)
        xr[i] = x[((size_t)bb*16 + kh*4 + i)*256 + o];
    __syncthreads();

    // ---- F2. O-contraction + epilogue -> sFbuf = x2 ----
    {
        float accX[4] = {0.f, 0.f, 0.f, 0.f};
        #pragma unroll
        for (int blk = 0; blk < 6; ++blk)
            #pragma unroll
            for (int l = 0; l < 16; ++l) {
                float y = bf2f(sY[l*1544 + blk*256 + o]);
                #pragma unroll
                for (int i = 0; i < 4; ++i)
                    accX[i] += sO[blk*256 + (kh*4 + i)*16 + l] * y;
            }
        float b0v = bias0[o], c0v = ce[o], c1v = ce[256+o], c2v = ce[512+o];
        #pragma unroll
        for (int i = 0; i < 4; ++i) {
            int k = kh*4 + i;
            float v = accX[i] + b0v
                    + sRsA[     k] * c0v
                    + sRsA[16 + k] * c1v
                    + sRsA[32 + k] * c2v
                    + xr[i];
            sFbuf[k][o] = v;
        }
    }
    __syncthreads();

    // ---- G. LN2 -> sNB (x2n bf16 chunks) ----
    {
        const int r = w, q = lane;
        float v[4];
        v[0] = sFbuf[r][q*4+0]; v[1] = sFbuf[r][q*4+1];
        v[2] = sFbuf[r][q*4+2]; v[3] = sFbuf[r][q*4+3];
        float sum = v[0]+v[1]+v[2]+v[3];
        float ss  = v[0]*v[0]+v[1]*v[1]+v[2]*v[2]+v[3]*v[3];
        #pragma unroll
        for (int of = 32; of; of >>= 1) { sum += __shfl_xor(sum, of); ss += __shfl_xor(ss, of); }
        float mean = sum * (1.f/256.f);
        float rstd = rsqrtf(ss*(1.f/256.f) - mean*mean + LNEPS);
        ushort4 pk;
        pk.x = f2bf((v[0]-mean)*rstd*n2g[q*4+0] + n2b[q*4+0]);
        pk.y = f2bf((v[1]-mean)*rstd*n2g[q*4+1] + n2b[q*4+1]);
        pk.z = f2bf((v[2]-mean)*rstd*n2g[q*4+2] + n2b[q*4+2]);
        pk.w = f2bf((v[3]-mean)*rstd*n2g[q*4+3] + n2b[q*4+3]);
        int kg = q >> 1;
        int swz = (kg & 24) | ((kg & 7) ^ (r & 7));
        *(ushort4*)&sNB[r*256 + swz*8 + (q & 1)*4] = pk;
    }
    __syncthreads();

    // ---- H. FFN1: wave w -> 4 n-tiles; h -> sH (frag layout) ----
    {
        U4 wb[8];
        #pragma unroll
        for (int kt = 0; kt < 8; ++kt)
            wb[kt].u4 = *(const uint4*)(w1t + (size_t)((w*4+0)*16 + rr)*256 + kt*32 + kq*8);
        #pragma unroll
        for (int j = 0; j < 4; ++j) {
            int nt = w*4 + j;
            f32x4 acc = {0.f, 0.f, 0.f, 0.f};
            #pragma unroll
            for (int kt = 0; kt < 8; ++kt) {
                int kg = kt*4 + kq;
                int swz = (kg & 24) | ((kg & 7) ^ (rr & 7));
                bf16x8 af = *(const bf16x8*)&sNB[rr*256 + swz*8];
                acc = __builtin_amdgcn_mfma_f32_16x16x32_bf16(af, wb[kt].bv, acc, 0, 0, 0);
            }
            if (j < 3) {
                #pragma unroll
                for (int kt = 0; kt < 8; ++kt)
                    wb[kt].u4 = *(const uint4*)(w1t + (size_t)((nt+1)*16 + rr)*256 + kt*32 + kq*8);
            }
            int n = nt*16 + rr;
            float bias = f1b[n];
            int hkg = n >> 3, hlo = n & 7;
            #pragma unroll
            for (int e = 0; e < 4; ++e) {
                int m = kq*4 + e;
                float v = acc[e] + bias;
                v = 0.5f * v * (1.f + erff(v * 0.70710678118654752f));
                int hswz = (hkg & 120) | ((hkg & 7) ^ (m & 7));
                sH[m*1024 + hswz*8 + hlo] = f2bf(v);
            }
        }
    }
    __syncthreads();

    // ---- I. FFN2: wave w -> 1 n-tile; out = x2 + h @ w2t^T + b2 ----
    {
        U4 qb[8];
        #pragma unroll
        for (int kt = 0; kt < 8; ++kt)
            qb[kt].u4 = *(const uint4*)(w2t + (size_t)(w*16 + rr)*1024 + kt*32 + kq*8);
        f32x4 acc = {0.f, 0.f, 0.f, 0.f};
        #pragma unroll
        for (int grp = 0; grp < 4; ++grp) {
            #pragma unroll
            for (int kt = 0; kt < 8; ++kt) {
                int hkg = (grp*8 + kt)*4 + kq;
                int hswz = (hkg & 120) | ((hkg & 7) ^ (rr & 7));
                bf16x8 af = *(const bf16x8*)&sH[rr*1024 + hswz*8];
                acc = __builtin_amdgcn_mfma_f32_16x16x32_bf16(af, qb[kt].bv, acc, 0, 0, 0);
            }
            if (grp < 3) {
                #pragma unroll
                for (int kt = 0; kt < 8; ++kt)
                    qb[kt].u4 = *(const uint4*)(w2t + (size_t)(w*16 + rr)*1024 + ((grp+1)*8 + kt)*32 + kq*8);
            }
        }
        int col = w*16 + rr;
        float bias = f2b[col];
        #pragma unroll
        for (int e = 0; e < 4; ++e) {
            int row = kq*4 + e;
            outp[((size_t)bb*16 + row)*256 + col] = acc[e] + bias + sFbuf[row][col];
        }
    }
}

extern "C" void kernel_launch(void* const* d_in, const int* in_sizes, int n_in,
                              void* d_out, int out_size, void* d_ws, size_t ws_size,
                              hipStream_t stream)
{
    (void)in_sizes; (void)n_in; (void)out_size;
    const float* x      = (const float*)d_in[0];
    const float* mask   = (const float*)d_in[1];
    const float* B1g    = (const float*)d_in[2];
    const float* B2g    = (const float*)d_in[3];
    const float* absB1  = (const float*)d_in[4];
    const int*   e_i    = (const int*)d_in[5];
    const int*   e_j    = (const int*)d_in[6];
    const int*   t_ij   = (const int*)d_in[7];
    const int*   t_jk   = (const int*)d_in[8];
    const int*   t_ik   = (const int*)d_in[9];
    const float* geom_w = (const float*)d_in[10];
    const float* geom_b = (const float*)d_in[11];
    const float* log_sc = (const float*)d_in[12];
    const float* wv0_w  = (const float*)d_in[13];
    const float* wv0_b  = (const float*)d_in[14];
    const float* wein_w = (const float*)d_in[15];
    const float* wein_b = (const float*)d_in[16];
    const float* out_w  = (const float*)d_in[17];
    const float* out_b  = (const float*)d_in[18];
    const float* n1_g   = (const float*)d_in[19];
    const float* n1_b   = (const float*)d_in[20];
    const float* n2_g   = (const float*)d_in[21];
    const float* n2_b   = (const float*)d_in[22];
    const float* ffn1_w = (const float*)d_in[23];
    const float* ffn1_b = (const float*)d_in[24];
    const float* ffn2_w = (const float*)d_in[25];
    const float* ffn2_b = (const float*)d_in[26];

    float* out = (float*)d_out;
    float* ws  = (float*)d_ws;
    if (ws_size < (size_t)WS_FLOATS * sizeof(float)) return;

    float* ce    = ws + CE_OFF;
    float* bias0 = ws + B0_OFF;
    float* C1    = ws + C1_OFF;
    float* r2    = ws + R2_OFF;
    uint4* ufrag  = (uint4*)(ws + UF_OFF);
    uint4* b1frag = (uint4*)(ws + B1F_OFF);
    uint4* gfrag  = (uint4*)(ws + GF_OFF);
    unsigned short* Qt  = (unsigned short*)(ws + QT_OFF);
    unsigned short* w1t = (unsigned short*)(ws + W1T_OFF);
    unsigned short* w2t = (unsigned short*)(ws + W2T_OFF);

    prep_k<<<653, 256, 0, stream>>>(wv0_w, wein_w, out_w, ffn1_w, ffn2_w,
                                    wv0_b, wein_b, out_b, B1g, absB1, B2g,
                                    Qt, w1t, w2t,
                                    ce, bias0, C1, r2,
                                    ufrag, b1frag, gfrag);
    k_mega<<<256, 1024, 0, stream>>>(x, mask, e_i, e_j, t_ij, t_jk, t_ik,
                                     geom_w, geom_b, log_sc, n1_g, n1_b, n2_g, n2_b,
                                     C1, r2, ufrag, b1frag, gfrag,
                                     Qt, bias0, ce,
                                     w1t, ffn1_b, w2t, ffn2_b, out);
}

// Round 9
// 102.935 us; speedup vs baseline: 1.1121x; 1.1121x over previous
//
#include <hip/hip_runtime.h>
#include <math.h>

#define TAUF  1.0e-4f
#define LNEPS 1.0e-5f

typedef __bf16 bf16x8 __attribute__((ext_vector_type(8)));
typedef float  f32x4  __attribute__((ext_vector_type(4)));

union U4 { uint4 u4; unsigned short us[8]; bf16x8 bv; };

static __device__ __forceinline__ unsigned short f2bf(float f) {
    union { float f; unsigned u; } v; v.f = f;
    unsigned r = v.u + 0x7fffu + ((v.u >> 16) & 1u);
    return (unsigned short)(r >> 16);
}
static __device__ __forceinline__ float bf2f(unsigned short h) {
    union { unsigned u; float f; } v; v.u = ((unsigned)h) << 16;
    return v.f;
}

// ---------------- workspace layout (float offsets, all 16B-aligned) ----------------
static const unsigned CE_OFF   = 0u;
static const unsigned B0_OFF   = 768u;
static const unsigned C0_OFF   = 1024u;
static const unsigned C1_OFF   = 1280u;
static const unsigned U_OFF    = 1536u;
static const unsigned SG_OFF   = 10496u;
static const unsigned R1_OFF   = 11056u;
static const unsigned R2_OFF   = 11072u;
static const unsigned UF_OFF   = 11088u;
static const unsigned B1F_OFF  = 15696u;
static const unsigned QT_OFF   = 16720u;     // 393216 bf16
static const unsigned W1T_OFF  = 213328u;    // 262144 bf16
static const unsigned W2T_OFF  = 344400u;    // 262144 bf16
static const unsigned WS_FLOATS = 475472u;   // ~1.9 MB

// ================= prep: ALL x-independent prep in ONE launch =================
// b <  96 : Qt MFMA GEMM (2-stage LDS, 3 barriers)
// b < 352 : transpose ffn1_w -> w1t bf16
// b < 608 : transpose ffn2_w -> w2t bf16
// b < 612 : bias folds (ce, bias0) -- LDS-staged streaming
// b < 648 : complex constants (C0,C1,r1,r2,sigma,U)
// b < 666 : ufrag (18, parallelized) ; b < 670 : b1frag (4)
__launch_bounds__(256)
__global__ void prep_k(const float* __restrict__ wv0_w, const float* __restrict__ wein_w,
                       const float* __restrict__ out_w,
                       const float* __restrict__ ffn1_w, const float* __restrict__ ffn2_w,
                       const float* __restrict__ wv0_b, const float* __restrict__ wein_b,
                       const float* __restrict__ out_b,
                       const float* __restrict__ B1g, const float* __restrict__ absB1,
                       const float* __restrict__ B2g,
                       unsigned short* __restrict__ Qt,
                       unsigned short* __restrict__ w1t, unsigned short* __restrict__ w2t,
                       float* __restrict__ ce, float* __restrict__ bias0,
                       float* __restrict__ C0, float* __restrict__ C1,
                       float* __restrict__ U, float* __restrict__ sigma,
                       float* __restrict__ r1, float* __restrict__ r2,
                       uint4* __restrict__ ufrag, uint4* __restrict__ b1frag)
{
    __shared__ float tile[32][33];
    __shared__ float sTf[128][68];
    __shared__ float sW[32][257];
    __shared__ unsigned short sFrag[64][8];
    int b = blockIdx.x, tid = threadIdx.x;
    if (b < 96) {
        // ---- Qt[row=blk*256+o][c'] = sum_d out_w[blk*256+d][o] * Wsel[c'][s*256+d] ----
        int by = b >> 2, bx = b & 3;
        int row0 = by * 64, col0 = bx * 64;
        int z = row0 >> 8, o0 = row0 & 255;
        int s = (z < 3) ? z : z - 3;
        const float* Wsel = (z < 3) ? wv0_w : wein_w;
        int lane = tid & 63, w = tid >> 6;
        int rr = lane & 15, kq = lane >> 4;
        f32x4 acc[4];
        #pragma unroll
        for (int cg = 0; cg < 4; ++cg) acc[cg] = 0.f;
        for (int st = 0; st < 2; ++st) {
            #pragma unroll
            for (int i = 0; i < 8; ++i) {
                int idx = i*256 + tid;
                int dd = idx >> 4, q = idx & 15;
                float4 v = *(const float4*)(out_w + (size_t)(z*256 + st*128 + dd)*256 + o0 + q*4);
                *(float4*)&sTf[dd][q*4] = v;
            }
            __syncthreads();
            for (int ks2 = 0; ks2 < 4; ++ks2) {
                int ks = st*4 + ks2;
                U4 av;
                #pragma unroll
                for (int j = 0; j < 8; ++j)
                    av.us[j] = f2bf(sTf[ks2*32 + kq*8 + j][w*16 + rr]);
                #pragma unroll
                for (int cg = 0; cg < 4; ++cg) {
                    const float* bp = Wsel + (size_t)(col0 + cg*16 + rr)*768 + s*256 + ks*32 + kq*8;
                    float4 b0 = *(const float4*)bp, b1 = *(const float4*)(bp + 4);
                    U4 bv;
                    bv.us[0]=f2bf(b0.x); bv.us[1]=f2bf(b0.y); bv.us[2]=f2bf(b0.z); bv.us[3]=f2bf(b0.w);
                    bv.us[4]=f2bf(b1.x); bv.us[5]=f2bf(b1.y); bv.us[6]=f2bf(b1.z); bv.us[7]=f2bf(b1.w);
                    acc[cg] = __builtin_amdgcn_mfma_f32_16x16x32_bf16(av.bv, bv.bv, acc[cg], 0, 0, 0);
                }
            }
            __syncthreads();
        }
        #pragma unroll
        for (int cg = 0; cg < 4; ++cg)
            #pragma unroll
            for (int e = 0; e < 4; ++e) {
                int row = row0 + w*16 + kq*4 + e;
                int col = col0 + cg*16 + rr;
                Qt[(size_t)row*256 + col] = f2bf(acc[cg][e]);
            }
    } else if (b < 352) {
        int bi = b - 96;
        int c0 = (bi & 31) * 32, r0 = (bi >> 5) * 32;
        int tx = tid & 31, ty = tid >> 5;
        #pragma unroll
        for (int i = 0; i < 4; ++i)
            tile[ty + i*8][tx] = ffn1_w[(size_t)(r0 + ty + i*8)*1024 + c0 + tx];
        __syncthreads();
        #pragma unroll
        for (int i = 0; i < 4; ++i)
            w1t[(size_t)(c0 + ty + i*8)*256 + r0 + tx] = f2bf(tile[tx][ty + i*8]);
    } else if (b < 608) {
        int bi = b - 352;
        int c0 = (bi & 7) * 32, r0 = (bi >> 3) * 32;
        int tx = tid & 31, ty = tid >> 5;
        #pragma unroll
        for (int i = 0; i < 4; ++i)
            tile[ty + i*8][tx] = ffn2_w[(size_t)(r0 + ty + i*8)*256 + c0 + tx];
        __syncthreads();
        #pragma unroll
        for (int i = 0; i < 4; ++i)
            w2t[(size_t)(c0 + ty + i*8)*1024 + r0 + tx] = f2bf(tile[tx][ty + i*8]);
    } else if (b < 612) {
        // ---- bias folds, LDS-staged: stream 32 rows of out_w at a time ----
        int which = b - 608;
        int o = tid;
        float acc = 0.f;
        if (which == 3) {
            for (int rc = 0; rc < 768; rc += 32) {
                #pragma unroll
                for (int i = 0; i < 32; ++i) sW[i][tid] = out_w[(size_t)(rc+i)*256 + tid];
                __syncthreads();
                #pragma unroll
                for (int i = 0; i < 32; ++i) acc += wv0_b[rc+i] * sW[i][tid];
                __syncthreads();
            }
            bias0[o] = out_b[o] + TAUF * acc;
        } else {
            int base = 768 + which*256;
            for (int rc = 0; rc < 256; rc += 32) {
                #pragma unroll
                for (int i = 0; i < 32; ++i) sW[i][tid] = out_w[(size_t)(base+rc+i)*256 + tid];
                __syncthreads();
                #pragma unroll
                for (int i = 0; i < 32; ++i) acc += wein_b[which*256 + rc+i] * sW[i][tid];
                __syncthreads();
            }
            ce[which*256 + o] = acc;
        }
    } else if (b < 648) {
        int sub = b - 612;
        if (sub == 0) {
            int p = tid >> 4, q = tid & 15;
            float c0 = 0.f, c1 = 0.f;
            for (int e = 0; e < 120; ++e) {
                float ap = absB1[p*120+e];
                c0 += ap * B1g[q*120+e];
                c1 += ap * absB1[q*120+e];
            }
            C0[tid] = c0; C1[tid] = c1;
            if (tid < 16) {
                float a = 0.f, bb = 0.f;
                for (int e = 0; e < 120; ++e) { a += B1g[tid*120+e]; bb += absB1[tid*120+e]; }
                r1[tid] = a; r2[tid] = bb;
            }
            for (int t = tid; t < 560; t += 256) {
                float s2 = 0.f;
                for (int e = 0; e < 120; ++e) s2 += B2g[e*560+t];
                sigma[t] = s2;
            }
        } else {
            int idx = (sub - 1) * 256 + tid;
            int p = idx / 560, t = idx % 560;
            float u = 0.f;
            for (int e = 0; e < 120; ++e) u += absB1[p*120+e] * B2g[e*560+t];
            U[idx] = u;
        }
    } else if (b < 666) {
        // ---- ufrag kt = b-648, parallelized: 512 items over 256 threads ----
        int kt = b - 648;
        #pragma unroll
        for (int it = 0; it < 2; ++it) {
            int item = it*256 + tid;           // 0..511
            int lane = item >> 3, j = item & 7;
            int col = lane & 15, kq = lane >> 4;
            int t = kt*32 + kq*8 + j;
            float v = 0.f;
            if (t < 560) {
                for (int e = 0; e < 120; ++e) v += absB1[col*120+e] * B2g[e*560+t];
            } else {
                int p = t - 560;
                for (int e = 0; e < 120; ++e) v += absB1[col*120+e] * B1g[p*120+e];
            }
            sFrag[lane][j] = f2bf(v);
        }
        __syncthreads();
        if (tid < 64) {
            U4 o;
            #pragma unroll
            for (int j = 0; j < 8; ++j) o.us[j] = sFrag[tid][j];
            ufrag[kt*64 + tid] = o.u4;
        }
    } else {
        if (tid < 64) {
            int lane = tid, col = lane & 15, kq = lane >> 4;
            int kt = b - 666;
            U4 o;
            #pragma unroll
            for (int j = 0; j < 8; ++j) {
                int e = kt*32 + kq*8 + j;
                o.us[j] = f2bf((e < 120) ? B1g[col*120 + e] : 0.f);
            }
            b1frag[kt*64 + lane] = o.u4;
        }
    }
}

// ============== k_mega: R6 structure (1024 threads, 16 waves) + setprio on MFMA clusters ==============
__launch_bounds__(1024)
__global__ void k_mega(const float* __restrict__ x, const float* __restrict__ mask,
                       const int* __restrict__ e_i, const int* __restrict__ e_j,
                       const int* __restrict__ t_ij, const int* __restrict__ t_jk,
                       const int* __restrict__ t_ik,
                       const float* __restrict__ geom_w, const float* __restrict__ geom_b,
                       const float* __restrict__ log_sc,
                       const float* __restrict__ n1_g, const float* __restrict__ n1_b,
                       const float* __restrict__ n2g, const float* __restrict__ n2b,
                       const float* __restrict__ C0, const float* __restrict__ C1,
                       const float* __restrict__ Up, const float* __restrict__ sg,
                       const float* __restrict__ r1, const float* __restrict__ r2,
                       const uint4* __restrict__ ufrag, const uint4* __restrict__ b1frag,
                       const unsigned short* __restrict__ Qt,
                       const float* __restrict__ bias0, const float* __restrict__ ce,
                       const unsigned short* __restrict__ w1t, const float* __restrict__ f1b,
                       const unsigned short* __restrict__ w2t, const float* __restrict__ f2b,
                       float* __restrict__ outp)
{
    __shared__ float sFbuf[16][264];           // xn (phases A-B), then x2 (F-I)
    __shared__ unsigned short sNB[16*256];     // bf16 xn chunks (A-F), then x2n chunks (G-H)
    __shared__ unsigned short sH[16*1024];     // h, frag layout (FFN2 A-frags)
    __shared__ float sP[16][17];
    __shared__ float sW1e[3][128];
    __shared__ float sW2e[3][576];
    __shared__ float sSig[560];
    __shared__ float sMask[16];
    __shared__ float sO[6*256];
    __shared__ float sRs[240];
    __shared__ float sRsA[48];
    __shared__ unsigned short sYb[16*264];     // Y blk tile (single buffer)

    const int bb = blockIdx.x, tid = threadIdx.x;
    const int w = tid >> 6, lane = tid & 63;
    const int rr = lane & 15, kq = lane >> 4;

    // ---- A. LayerNorm 1: wave w = row w, 64 lanes x 4 elems ----
    {
        const int r = w, q = lane;
        const float* row = x + ((size_t)bb*16 + r)*256 + q*4;
        float4 va = *(const float4*)row;
        float v[4] = {va.x, va.y, va.z, va.w};
        float sum = v[0]+v[1]+v[2]+v[3];
        float ss  = v[0]*v[0]+v[1]*v[1]+v[2]*v[2]+v[3]*v[3];
        #pragma unroll
        for (int o = 32; o; o >>= 1) { sum += __shfl_xor(sum, o); ss += __shfl_xor(ss, o); }
        float mean = sum * (1.f/256.f);
        float rstd = rsqrtf(ss*(1.f/256.f) - mean*mean + LNEPS);
        ushort4 pk;
        float xv0 = (v[0]-mean)*rstd*n1_g[q*4+0] + n1_b[q*4+0];
        float xv1 = (v[1]-mean)*rstd*n1_g[q*4+1] + n1_b[q*4+1];
        float xv2 = (v[2]-mean)*rstd*n1_g[q*4+2] + n1_b[q*4+2];
        float xv3 = (v[3]-mean)*rstd*n1_g[q*4+3] + n1_b[q*4+3];
        sFbuf[r][q*4+0] = xv0; sFbuf[r][q*4+1] = xv1;
        sFbuf[r][q*4+2] = xv2; sFbuf[r][q*4+3] = xv3;
        pk.x = f2bf(xv0); pk.y = f2bf(xv1); pk.z = f2bf(xv2); pk.w = f2bf(xv3);
        int kg = q >> 1;
        int swz = (kg & 24) | ((kg & 7) ^ (r & 7));
        *(ushort4*)&sNB[r*256 + swz*8 + (q & 1)*4] = pk;
        if (tid < 16) sMask[tid] = mask[bb*16 + tid];
        for (int i = tid; i < 560; i += 1024) sSig[i] = sg[i];
    }
    __syncthreads();

    // ---- B. P = xn @ geom_w + geom_b: (r, g, quarter) ----
    {
        const int r = w, g = (lane >> 2) & 15, quarter = lane & 3;
        const int cb = quarter * 64;
        float a0 = 0.f, a1 = 0.f, a2 = 0.f, a3 = 0.f;
        for (int c = 0; c < 64; c += 4) {
            a0 += sFbuf[r][cb+c+0] * geom_w[(cb+c+0)*16 + g];
            a1 += sFbuf[r][cb+c+1] * geom_w[(cb+c+1)*16 + g];
            a2 += sFbuf[r][cb+c+2] * geom_w[(cb+c+2)*16 + g];
            a3 += sFbuf[r][cb+c+3] * geom_w[(cb+c+3)*16 + g];
        }
        float p = (a0+a1) + (a2+a3);
        p += __shfl_xor(p, 1);
        p += __shfl_xor(p, 2);
        if (quarter == 0) sP[r][g] = p + geom_b[g];
    }
    __syncthreads();

    // ---- C. W1: e = tid>>3, s = tid&7 ----
    {
        int e = tid >> 3, s = tid & 7;
        if (e < 120 && s < 3) {
            int i0 = e_i[e], j0 = e_j[e];
            float d2 = 0.f;
            #pragma unroll
            for (int m = 0; m < 16; ++m) { float dd = sP[i0][m] - sP[j0][m]; d2 += dd*dd; }
            float mm = sMask[i0]*sMask[j0];
            d2 *= mm*mm;
            float sc = expf(log_sc[s]);
            sW1e[s][e] = expf(-d2/(2.f*sc*sc + 1e-8f)) * mm;
        }
        if (tid < 24) sW1e[tid >> 3][120 + (tid & 7)] = 0.f;
    }
    __syncthreads();

    // ---- D. W2 + mask extension ----
    if (tid < 560) {
        int t = tid;
        int a = t_ij[t], b2 = t_jk[t], c2 = t_ik[t];
        #pragma unroll
        for (int s = 0; s < 3; ++s) sW2e[s][t] = sW1e[s][a]*sW1e[s][b2]*sW1e[s][c2];
    }
    if (tid < 48) sW2e[tid >> 4][560 + (tid & 15)] = sMask[tid & 15];
    __syncthreads();

    // ---- E. waves 0-2: edge O; wave 3: node O; waves 4-7: rsA partials; 8-15 idle ----
    if (w < 3) {
        int s = w;
        f32x4 acc = {0.f, 0.f, 0.f, 0.f};
        __builtin_amdgcn_s_setprio(1);
        for (int kt = 0; kt < 18; ++kt) {
            U4 ub; ub.u4 = ufrag[kt*64 + lane];
            const float4* w4 = (const float4*)&sW2e[s][kt*32 + kq*8];
            float4 wa = w4[0], wb = w4[1];
            U4 av;
            av.us[0] = f2bf(wa.x * bf2f(ub.us[0]));
            av.us[1] = f2bf(wa.y * bf2f(ub.us[1]));
            av.us[2] = f2bf(wa.z * bf2f(ub.us[2]));
            av.us[3] = f2bf(wa.w * bf2f(ub.us[3]));
            av.us[4] = f2bf(wb.x * bf2f(ub.us[4]));
            av.us[5] = f2bf(wb.y * bf2f(ub.us[5]));
            av.us[6] = f2bf(wb.z * bf2f(ub.us[6]));
            av.us[7] = f2bf(wb.w * bf2f(ub.us[7]));
            acc = __builtin_amdgcn_mfma_f32_16x16x32_bf16(av.bv, ub.bv, acc, 0, 0, 0);
        }
        __builtin_amdgcn_s_setprio(0);
        #pragma unroll
        for (int e = 0; e < 4; ++e) {
            int row = kq*4 + e;
            sO[(3+s)*256 + row*16 + rr] = acc[e] + TAUF*C1[row*16 + rr];
        }
    } else if (w == 3) {
        f32x4 acc3[3];
        acc3[0] = 0.f; acc3[1] = 0.f; acc3[2] = 0.f;
        __builtin_amdgcn_s_setprio(1);
        for (int kt = 0; kt < 4; ++kt) {
            U4 ub; ub.u4 = b1frag[kt*64 + lane];
            float uf[8];
            #pragma unroll
            for (int j = 0; j < 8; ++j) uf[j] = bf2f(ub.us[j]);
            #pragma unroll
            for (int s = 0; s < 3; ++s) {
                const float4* w4 = (const float4*)&sW1e[s][kt*32 + kq*8];
                float4 wa = w4[0], wb = w4[1];
                U4 av;
                av.us[0] = f2bf(wa.x * uf[0]);
                av.us[1] = f2bf(wa.y * uf[1]);
                av.us[2] = f2bf(wa.z * uf[2]);
                av.us[3] = f2bf(wa.w * uf[3]);
                av.us[4] = f2bf(wb.x * uf[4]);
                av.us[5] = f2bf(wb.y * uf[5]);
                av.us[6] = f2bf(wb.z * uf[6]);
                av.us[7] = f2bf(wb.w * uf[7]);
                acc3[s] = __builtin_amdgcn_mfma_f32_16x16x32_bf16(av.bv, ub.bv, acc3[s], 0, 0, 0);
            }
        }
        __builtin_amdgcn_s_setprio(0);
        #pragma unroll
        for (int s = 0; s < 3; ++s)
            #pragma unroll
            for (int e = 0; e < 4; ++e) {
                int row = kq*4 + e;
                sO[s*256 + row*16 + rr] = acc3[s][e] + ((row == rr) ? TAUF : 0.f);
            }
    } else if (w < 8) {
        int idx = tid - 256;
        if (idx < 240) {
            int s = idx / 80, rem = idx % 80;
            int k = rem / 5, ch = rem % 5;
            float p = 0.f;
            int t0 = ch * 112;
            for (int i = 0; i < 112; ++i) {
                int t = t0 + i;
                p += sW2e[s][t] * sSig[t] * Up[k*560 + t];
            }
            sRs[(s*16 + k)*5 + ch] = p;
        }
    }
    __syncthreads();

    if (tid < 48) {
        int k = tid & 15;
        float a = TAUF * r2[k];
        #pragma unroll
        for (int p = 0; p < 16; ++p) a += C0[k*16 + p] * sMask[p] * r1[p];
        #pragma unroll
        for (int ch = 0; ch < 5; ++ch) a += sRs[tid*5 + ch];
        sRsA[tid] = a;
    }

    // ---- F. blk-wise Y-GEMM (wave w -> 16 cols) + O-contraction; Qt frags reg-prefetched ----
    {
        const int o = tid & 255, kh = tid >> 8;    // kh: 4 row-quads
        float accX[4] = {0.f, 0.f, 0.f, 0.f};
        float xr[4];
        #pragma unroll
        for (int i = 0; i < 4; ++i)
            xr[i] = x[((size_t)bb*16 + kh*4 + i)*256 + o];
        U4 qf[8];
        #pragma unroll
        for (int kt = 0; kt < 8; ++kt)
            qf[kt].u4 = *(const uint4*)(Qt + ((size_t)(0*256 + w*16 + rr))*256 + kt*32 + kq*8);
        for (int blk = 0; blk < 6; ++blk) {
            f32x4 ya = {0.f, 0.f, 0.f, 0.f};
            __builtin_amdgcn_s_setprio(1);
            #pragma unroll
            for (int kt = 0; kt < 8; ++kt) {
                int kg = kt*4 + kq;
                int swz = (kg & 24) | ((kg & 7) ^ (rr & 7));
                bf16x8 af = *(const bf16x8*)&sNB[rr*256 + swz*8];
                ya = __builtin_amdgcn_mfma_f32_16x16x32_bf16(af, qf[kt].bv, ya, 0, 0, 0);
            }
            __builtin_amdgcn_s_setprio(0);
            if (blk < 5) {
                #pragma unroll
                for (int kt = 0; kt < 8; ++kt)
                    qf[kt].u4 = *(const uint4*)(Qt + ((size_t)((blk+1)*256 + w*16 + rr))*256 + kt*32 + kq*8);
            }
            __syncthreads();                       // prev contraction done reading sYb
            #pragma unroll
            for (int e = 0; e < 4; ++e) {
                int l = kq*4 + e;
                sYb[l*264 + w*16 + rr] = f2bf(ya[e]);
            }
            __syncthreads();
            #pragma unroll
            for (int l = 0; l < 16; ++l) {
                float y = bf2f(sYb[l*264 + o]);
                #pragma unroll
                for (int i = 0; i < 4; ++i)
                    accX[i] += sO[blk*256 + (kh*4 + i)*16 + l] * y;
            }
        }
        __syncthreads();
        float b0v = bias0[o], c0v = ce[o], c1v = ce[256+o], c2v = ce[512+o];
        #pragma unroll
        for (int i = 0; i < 4; ++i) {
            int k = kh*4 + i;
            float v = accX[i] + b0v
                    + sRsA[     k] * c0v
                    + sRsA[16 + k] * c1v
                    + sRsA[32 + k] * c2v
                    + xr[i];
            sFbuf[k][o] = v;                       // x2 (xn dead)
        }
    }
    __syncthreads();

    // ---- G. LN2 -> sNB (x2n bf16 chunks) ----
    {
        const int r = w, q = lane;
        float v[4];
        v[0] = sFbuf[r][q*4+0]; v[1] = sFbuf[r][q*4+1];
        v[2] = sFbuf[r][q*4+2]; v[3] = sFbuf[r][q*4+3];
        float sum = v[0]+v[1]+v[2]+v[3];
        float ss  = v[0]*v[0]+v[1]*v[1]+v[2]*v[2]+v[3]*v[3];
        #pragma unroll
        for (int o = 32; o; o >>= 1) { sum += __shfl_xor(sum, o); ss += __shfl_xor(ss, o); }
        float mean = sum * (1.f/256.f);
        float rstd = rsqrtf(ss*(1.f/256.f) - mean*mean + LNEPS);
        ushort4 pk;
        pk.x = f2bf((v[0]-mean)*rstd*n2g[q*4+0] + n2b[q*4+0]);
        pk.y = f2bf((v[1]-mean)*rstd*n2g[q*4+1] + n2b[q*4+1]);
        pk.z = f2bf((v[2]-mean)*rstd*n2g[q*4+2] + n2b[q*4+2]);
        pk.w = f2bf((v[3]-mean)*rstd*n2g[q*4+3] + n2b[q*4+3]);
        int kg = q >> 1;
        int swz = (kg & 24) | ((kg & 7) ^ (r & 7));
        *(ushort4*)&sNB[r*256 + swz*8 + (q & 1)*4] = pk;
    }
    __syncthreads();

    // ---- H. FFN1: wave w -> 4 n-tiles; h -> sH (frag layout) ----
    {
        U4 wb[8];
        #pragma unroll
        for (int kt = 0; kt < 8; ++kt)
            wb[kt].u4 = *(const uint4*)(w1t + (size_t)((w*4+0)*16 + rr)*256 + kt*32 + kq*8);
        #pragma unroll
        for (int j = 0; j < 4; ++j) {
            int nt = w*4 + j;
            f32x4 acc = {0.f, 0.f, 0.f, 0.f};
            __builtin_amdgcn_s_setprio(1);
            #pragma unroll
            for (int kt = 0; kt < 8; ++kt) {
                int kg = kt*4 + kq;
                int swz = (kg & 24) | ((kg & 7) ^ (rr & 7));
                bf16x8 af = *(const bf16x8*)&sNB[rr*256 + swz*8];
                acc = __builtin_amdgcn_mfma_f32_16x16x32_bf16(af, wb[kt].bv, acc, 0, 0, 0);
            }
            __builtin_amdgcn_s_setprio(0);
            if (j < 3) {
                #pragma unroll
                for (int kt = 0; kt < 8; ++kt)
                    wb[kt].u4 = *(const uint4*)(w1t + (size_t)((nt+1)*16 + rr)*256 + kt*32 + kq*8);
            }
            int n = nt*16 + rr;
            float bias = f1b[n];
            int hkg = n >> 3, hlo = n & 7;
            #pragma unroll
            for (int e = 0; e < 4; ++e) {
                int m = kq*4 + e;
                float v = acc[e] + bias;
                v = 0.5f * v * (1.f + erff(v * 0.70710678118654752f));
                int hswz = (hkg & 120) | ((hkg & 7) ^ (m & 7));
                sH[m*1024 + hswz*8 + hlo] = f2bf(v);
            }
        }
    }
    __syncthreads();

    // ---- I. FFN2: wave w -> 1 n-tile; out = x2 + h @ w2t^T + b2 ----
    {
        U4 qb[8];
        #pragma unroll
        for (int kt = 0; kt < 8; ++kt)
            qb[kt].u4 = *(const uint4*)(w2t + (size_t)(w*16 + rr)*1024 + kt*32 + kq*8);
        f32x4 acc = {0.f, 0.f, 0.f, 0.f};
        #pragma unroll
        for (int grp = 0; grp < 4; ++grp) {
            __builtin_amdgcn_s_setprio(1);
            #pragma unroll
            for (int kt = 0; kt < 8; ++kt) {
                int hkg = (grp*8 + kt)*4 + kq;
                int hswz = (hkg & 120) | ((hkg & 7) ^ (rr & 7));
                bf16x8 af = *(const bf16x8*)&sH[rr*1024 + hswz*8];
                acc = __builtin_amdgcn_mfma_f32_16x16x32_bf16(af, qb[kt].bv, acc, 0, 0, 0);
            }
            __builtin_amdgcn_s_setprio(0);
            if (grp < 3) {
                #pragma unroll
                for (int kt = 0; kt < 8; ++kt)
                    qb[kt].u4 = *(const uint4*)(w2t + (size_t)(w*16 + rr)*1024 + ((grp+1)*8 + kt)*32 + kq*8);
            }
        }
        int col = w*16 + rr;
        float bias = f2b[col];
        #pragma unroll
        for (int e = 0; e < 4; ++e) {
            int row = kq*4 + e;
            outp[((size_t)bb*16 + row)*256 + col] = acc[e] + bias + sFbuf[row][col];
        }
    }
}

extern "C" void kernel_launch(void* const* d_in, const int* in_sizes, int n_in,
                              void* d_out, int out_size, void* d_ws, size_t ws_size,
                              hipStream_t stream)
{
    (void)in_sizes; (void)n_in; (void)out_size;
    const float* x      = (const float*)d_in[0];
    const float* mask   = (const float*)d_in[1];
    const float* B1g    = (const float*)d_in[2];
    const float* B2g    = (const float*)d_in[3];
    const float* absB1  = (const float*)d_in[4];
    const int*   e_i    = (const int*)d_in[5];
    const int*   e_j    = (const int*)d_in[6];
    const int*   t_ij   = (const int*)d_in[7];
    const int*   t_jk   = (const int*)d_in[8];
    const int*   t_ik   = (const int*)d_in[9];
    const float* geom_w = (const float*)d_in[10];
    const float* geom_b = (const float*)d_in[11];
    const float* log_sc = (const float*)d_in[12];
    const float* wv0_w  = (const float*)d_in[13];
    const float* wv0_b  = (const float*)d_in[14];
    const float* wein_w = (const float*)d_in[15];
    const float* wein_b = (const float*)d_in[16];
    const float* out_w  = (const float*)d_in[17];
    const float* out_b  = (const float*)d_in[18];
    const float* n1_g   = (const float*)d_in[19];
    const float* n1_b   = (const float*)d_in[20];
    const float* n2_g   = (const float*)d_in[21];
    const float* n2_b   = (const float*)d_in[22];
    const float* ffn1_w = (const float*)d_in[23];
    const float* ffn1_b = (const float*)d_in[24];
    const float* ffn2_w = (const float*)d_in[25];
    const float* ffn2_b = (const float*)d_in[26];

    float* out = (float*)d_out;
    float* ws  = (float*)d_ws;
    if (ws_size < (size_t)WS_FLOATS * sizeof(float)) return;

    float* ce    = ws + CE_OFF;
    float* bias0 = ws + B0_OFF;
    float* C0    = ws + C0_OFF;
    float* C1    = ws + C1_OFF;
    float* U     = ws + U_OFF;
    float* sg    = ws + SG_OFF;
    float* r1    = ws + R1_OFF;
    float* r2    = ws + R2_OFF;
    uint4* ufrag  = (uint4*)(ws + UF_OFF);
    uint4* b1frag = (uint4*)(ws + B1F_OFF);
    unsigned short* Qt  = (unsigned short*)(ws + QT_OFF);
    unsigned short* w1t = (unsigned short*)(ws + W1T_OFF);
    unsigned short* w2t = (unsigned short*)(ws + W2T_OFF);

    prep_k<<<670, 256, 0, stream>>>(wv0_w, wein_w, out_w, ffn1_w, ffn2_w,
                                    wv0_b, wein_b, out_b, B1g, absB1, B2g,
                                    Qt, w1t, w2t,
                                    ce, bias0, C0, C1, U, sg, r1, r2,
                                    ufrag, b1frag);
    k_mega<<<256, 1024, 0, stream>>>(x, mask, e_i, e_j, t_ij, t_jk, t_ik,
                                     geom_w, geom_b, log_sc, n1_g, n1_b, n2_g, n2_b,
                                     C0, C1, U, sg, r1, r2, ufrag, b1frag,
                                     Qt, bias0, ce,
                                     w1t, ffn1_b, w2t, ffn2_b, out);
}

// Round 10
// 102.461 us; speedup vs baseline: 1.1172x; 1.0046x over previous
//
#include <hip/hip_runtime.h>
#include <math.h>

#define TAUF  1.0e-4f
#define LNEPS 1.0e-5f

typedef __bf16 bf16x8 __attribute__((ext_vector_type(8)));
typedef float  f32x4  __attribute__((ext_vector_type(4)));

union U4 { uint4 u4; unsigned short us[8]; bf16x8 bv; };

static __device__ __forceinline__ unsigned short f2bf(float f) {
    union { float f; unsigned u; } v; v.f = f;
    unsigned r = v.u + 0x7fffu + ((v.u >> 16) & 1u);
    return (unsigned short)(r >> 16);
}
static __device__ __forceinline__ float bf2f(unsigned short h) {
    union { unsigned u; float f; } v; v.u = ((unsigned)h) << 16;
    return v.f;
}

// ---------------- workspace layout (float offsets, all 16B-aligned) ----------------
static const unsigned CE_OFF   = 0u;
static const unsigned B0_OFF   = 768u;
static const unsigned C0_OFF   = 1024u;
static const unsigned C1_OFF   = 1280u;
static const unsigned U_OFF    = 1536u;
static const unsigned SG_OFF   = 10496u;
static const unsigned R1_OFF   = 11056u;
static const unsigned R2_OFF   = 11072u;
static const unsigned UF_OFF   = 11088u;
static const unsigned B1F_OFF  = 15696u;
static const unsigned QT_OFF   = 16720u;     // 393216 bf16
static const unsigned W1T_OFF  = 213328u;    // 262144 bf16
static const unsigned W2T_OFF  = 344400u;    // 262144 bf16
static const unsigned WS_FLOATS = 475472u;   // ~1.9 MB

// ================= prep: ALL x-independent prep in ONE launch (R9 structure) =================
__launch_bounds__(256, 2)
__global__ void prep_k(const float* __restrict__ wv0_w, const float* __restrict__ wein_w,
                       const float* __restrict__ out_w,
                       const float* __restrict__ ffn1_w, const float* __restrict__ ffn2_w,
                       const float* __restrict__ wv0_b, const float* __restrict__ wein_b,
                       const float* __restrict__ out_b,
                       const float* __restrict__ B1g, const float* __restrict__ absB1,
                       const float* __restrict__ B2g,
                       unsigned short* __restrict__ Qt,
                       unsigned short* __restrict__ w1t, unsigned short* __restrict__ w2t,
                       float* __restrict__ ce, float* __restrict__ bias0,
                       float* __restrict__ C0, float* __restrict__ C1,
                       float* __restrict__ U, float* __restrict__ sigma,
                       float* __restrict__ r1, float* __restrict__ r2,
                       uint4* __restrict__ ufrag, uint4* __restrict__ b1frag)
{
    __shared__ float tile[32][33];
    __shared__ float sTf[128][68];
    __shared__ float sW[32][257];
    __shared__ unsigned short sFrag[64][8];
    int b = blockIdx.x, tid = threadIdx.x;
    if (b < 96) {
        int by = b >> 2, bx = b & 3;
        int row0 = by * 64, col0 = bx * 64;
        int z = row0 >> 8, o0 = row0 & 255;
        int s = (z < 3) ? z : z - 3;
        const float* Wsel = (z < 3) ? wv0_w : wein_w;
        int lane = tid & 63, w = tid >> 6;
        int rr = lane & 15, kq = lane >> 4;
        f32x4 acc[4];
        #pragma unroll
        for (int cg = 0; cg < 4; ++cg) acc[cg] = 0.f;
        for (int st = 0; st < 2; ++st) {
            #pragma unroll
            for (int i = 0; i < 8; ++i) {
                int idx = i*256 + tid;
                int dd = idx >> 4, q = idx & 15;
                float4 v = *(const float4*)(out_w + (size_t)(z*256 + st*128 + dd)*256 + o0 + q*4);
                *(float4*)&sTf[dd][q*4] = v;
            }
            __syncthreads();
            for (int ks2 = 0; ks2 < 4; ++ks2) {
                int ks = st*4 + ks2;
                U4 av;
                #pragma unroll
                for (int j = 0; j < 8; ++j)
                    av.us[j] = f2bf(sTf[ks2*32 + kq*8 + j][w*16 + rr]);
                #pragma unroll
                for (int cg = 0; cg < 4; ++cg) {
                    const float* bp = Wsel + (size_t)(col0 + cg*16 + rr)*768 + s*256 + ks*32 + kq*8;
                    float4 b0 = *(const float4*)bp, b1 = *(const float4*)(bp + 4);
                    U4 bv;
                    bv.us[0]=f2bf(b0.x); bv.us[1]=f2bf(b0.y); bv.us[2]=f2bf(b0.z); bv.us[3]=f2bf(b0.w);
                    bv.us[4]=f2bf(b1.x); bv.us[5]=f2bf(b1.y); bv.us[6]=f2bf(b1.z); bv.us[7]=f2bf(b1.w);
                    acc[cg] = __builtin_amdgcn_mfma_f32_16x16x32_bf16(av.bv, bv.bv, acc[cg], 0, 0, 0);
                }
            }
            __syncthreads();
        }
        #pragma unroll
        for (int cg = 0; cg < 4; ++cg)
            #pragma unroll
            for (int e = 0; e < 4; ++e) {
                int row = row0 + w*16 + kq*4 + e;
                int col = col0 + cg*16 + rr;
                Qt[(size_t)row*256 + col] = f2bf(acc[cg][e]);
            }
    } else if (b < 352) {
        int bi = b - 96;
        int c0 = (bi & 31) * 32, r0 = (bi >> 5) * 32;
        int tx = tid & 31, ty = tid >> 5;
        #pragma unroll
        for (int i = 0; i < 4; ++i)
            tile[ty + i*8][tx] = ffn1_w[(size_t)(r0 + ty + i*8)*1024 + c0 + tx];
        __syncthreads();
        #pragma unroll
        for (int i = 0; i < 4; ++i)
            w1t[(size_t)(c0 + ty + i*8)*256 + r0 + tx] = f2bf(tile[tx][ty + i*8]);
    } else if (b < 608) {
        int bi = b - 352;
        int c0 = (bi & 7) * 32, r0 = (bi >> 3) * 32;
        int tx = tid & 31, ty = tid >> 5;
        #pragma unroll
        for (int i = 0; i < 4; ++i)
            tile[ty + i*8][tx] = ffn2_w[(size_t)(r0 + ty + i*8)*256 + c0 + tx];
        __syncthreads();
        #pragma unroll
        for (int i = 0; i < 4; ++i)
            w2t[(size_t)(c0 + ty + i*8)*1024 + r0 + tx] = f2bf(tile[tx][ty + i*8]);
    } else if (b < 612) {
        int which = b - 608;
        int o = tid;
        float acc = 0.f;
        if (which == 3) {
            for (int rc = 0; rc < 768; rc += 32) {
                #pragma unroll
                for (int i = 0; i < 32; ++i) sW[i][tid] = out_w[(size_t)(rc+i)*256 + tid];
                __syncthreads();
                #pragma unroll
                for (int i = 0; i < 32; ++i) acc += wv0_b[rc+i] * sW[i][tid];
                __syncthreads();
            }
            bias0[o] = out_b[o] + TAUF * acc;
        } else {
            int base = 768 + which*256;
            for (int rc = 0; rc < 256; rc += 32) {
                #pragma unroll
                for (int i = 0; i < 32; ++i) sW[i][tid] = out_w[(size_t)(base+rc+i)*256 + tid];
                __syncthreads();
                #pragma unroll
                for (int i = 0; i < 32; ++i) acc += wein_b[which*256 + rc+i] * sW[i][tid];
                __syncthreads();
            }
            ce[which*256 + o] = acc;
        }
    } else if (b < 648) {
        int sub = b - 612;
        if (sub == 0) {
            int p = tid >> 4, q = tid & 15;
            float c0 = 0.f, c1 = 0.f;
            for (int e = 0; e < 120; ++e) {
                float ap = absB1[p*120+e];
                c0 += ap * B1g[q*120+e];
                c1 += ap * absB1[q*120+e];
            }
            C0[tid] = c0; C1[tid] = c1;
            if (tid < 16) {
                float a = 0.f, bb = 0.f;
                for (int e = 0; e < 120; ++e) { a += B1g[tid*120+e]; bb += absB1[tid*120+e]; }
                r1[tid] = a; r2[tid] = bb;
            }
            for (int t = tid; t < 560; t += 256) {
                float s2 = 0.f;
                for (int e = 0; e < 120; ++e) s2 += B2g[e*560+t];
                sigma[t] = s2;
            }
        } else {
            int idx = (sub - 1) * 256 + tid;
            int p = idx / 560, t = idx % 560;
            float u = 0.f;
            for (int e = 0; e < 120; ++e) u += absB1[p*120+e] * B2g[e*560+t];
            U[idx] = u;
        }
    } else if (b < 666) {
        int kt = b - 648;
        #pragma unroll
        for (int it = 0; it < 2; ++it) {
            int item = it*256 + tid;
            int lane = item >> 3, j = item & 7;
            int col = lane & 15, kq = lane >> 4;
            int t = kt*32 + kq*8 + j;
            float v = 0.f;
            if (t < 560) {
                for (int e = 0; e < 120; ++e) v += absB1[col*120+e] * B2g[e*560+t];
            } else {
                int p = t - 560;
                for (int e = 0; e < 120; ++e) v += absB1[col*120+e] * B1g[p*120+e];
            }
            sFrag[lane][j] = f2bf(v);
        }
        __syncthreads();
        if (tid < 64) {
            U4 o;
            #pragma unroll
            for (int j = 0; j < 8; ++j) o.us[j] = sFrag[tid][j];
            ufrag[kt*64 + tid] = o.u4;
        }
    } else {
        if (tid < 64) {
            int lane = tid, col = lane & 15, kq = lane >> 4;
            int kt = b - 666;
            U4 o;
            #pragma unroll
            for (int j = 0; j < 8; ++j) {
                int e = kt*32 + kq*8 + j;
                o.us[j] = f2bf((e < 120) ? B1g[col*120 + e] : 0.f);
            }
            b1frag[kt*64 + lane] = o.u4;
        }
    }
}

// ============== k_mega: R9 structure + launch_bounds(1024,4) + dbuf sYb + vectorized B ==============
__launch_bounds__(1024, 4)
__global__ void k_mega(const float* __restrict__ x, const float* __restrict__ mask,
                       const int* __restrict__ e_i, const int* __restrict__ e_j,
                       const int* __restrict__ t_ij, const int* __restrict__ t_jk,
                       const int* __restrict__ t_ik,
                       const float* __restrict__ geom_w, const float* __restrict__ geom_b,
                       const float* __restrict__ log_sc,
                       const float* __restrict__ n1_g, const float* __restrict__ n1_b,
                       const float* __restrict__ n2g, const float* __restrict__ n2b,
                       const float* __restrict__ C0, const float* __restrict__ C1,
                       const float* __restrict__ Up, const float* __restrict__ sg,
                       const float* __restrict__ r1, const float* __restrict__ r2,
                       const uint4* __restrict__ ufrag, const uint4* __restrict__ b1frag,
                       const unsigned short* __restrict__ Qt,
                       const float* __restrict__ bias0, const float* __restrict__ ce,
                       const unsigned short* __restrict__ w1t, const float* __restrict__ f1b,
                       const unsigned short* __restrict__ w2t, const float* __restrict__ f2b,
                       float* __restrict__ outp)
{
    __shared__ float sFbuf[16][264];           // xn (phases A-B), then x2 (F-I)
    __shared__ unsigned short sNB[16*256];     // bf16 xn chunks (A-F), then x2n chunks (G-H)
    __shared__ unsigned short sH[16*1024];     // h, frag layout (FFN2 A-frags)
    __shared__ float sP[16][17];
    __shared__ float sW1e[3][128];
    __shared__ float sW2e[3][576];
    __shared__ float sSig[560];
    __shared__ float sMask[16];
    __shared__ float sO[6*256];
    __shared__ float sRs[240];
    __shared__ float sRsA[48];
    __shared__ unsigned short sYb[2][16*264];  // Y blk tile, double-buffered

    const int bb = blockIdx.x, tid = threadIdx.x;
    const int w = tid >> 6, lane = tid & 63;
    const int rr = lane & 15, kq = lane >> 4;

    // ---- A. LayerNorm 1: wave w = row w, 64 lanes x 4 elems ----
    {
        const int r = w, q = lane;
        const float* row = x + ((size_t)bb*16 + r)*256 + q*4;
        float4 va = *(const float4*)row;
        float v[4] = {va.x, va.y, va.z, va.w};
        float sum = v[0]+v[1]+v[2]+v[3];
        float ss  = v[0]*v[0]+v[1]*v[1]+v[2]*v[2]+v[3]*v[3];
        #pragma unroll
        for (int o = 32; o; o >>= 1) { sum += __shfl_xor(sum, o); ss += __shfl_xor(ss, o); }
        float mean = sum * (1.f/256.f);
        float rstd = rsqrtf(ss*(1.f/256.f) - mean*mean + LNEPS);
        ushort4 pk;
        float xv0 = (v[0]-mean)*rstd*n1_g[q*4+0] + n1_b[q*4+0];
        float xv1 = (v[1]-mean)*rstd*n1_g[q*4+1] + n1_b[q*4+1];
        float xv2 = (v[2]-mean)*rstd*n1_g[q*4+2] + n1_b[q*4+2];
        float xv3 = (v[3]-mean)*rstd*n1_g[q*4+3] + n1_b[q*4+3];
        sFbuf[r][q*4+0] = xv0; sFbuf[r][q*4+1] = xv1;
        sFbuf[r][q*4+2] = xv2; sFbuf[r][q*4+3] = xv3;
        pk.x = f2bf(xv0); pk.y = f2bf(xv1); pk.z = f2bf(xv2); pk.w = f2bf(xv3);
        int kg = q >> 1;
        int swz = (kg & 24) | ((kg & 7) ^ (r & 7));
        *(ushort4*)&sNB[r*256 + swz*8 + (q & 1)*4] = pk;
        if (tid < 16) sMask[tid] = mask[bb*16 + tid];
        for (int i = tid; i < 560; i += 1024) sSig[i] = sg[i];
    }
    __syncthreads();

    // ---- B. P = xn @ geom_w + geom_b: (r, g, quarter), float4 broadcast reads ----
    {
        const int r = w, g = (lane >> 2) & 15, quarter = lane & 3;
        const int cb = quarter * 64;
        float a0 = 0.f, a1 = 0.f, a2 = 0.f, a3 = 0.f;
        for (int c = 0; c < 64; c += 4) {
            float4 xv = *(const float4*)&sFbuf[r][cb + c];
            a0 += xv.x * geom_w[(cb+c+0)*16 + g];
            a1 += xv.y * geom_w[(cb+c+1)*16 + g];
            a2 += xv.z * geom_w[(cb+c+2)*16 + g];
            a3 += xv.w * geom_w[(cb+c+3)*16 + g];
        }
        float p = (a0+a1) + (a2+a3);
        p += __shfl_xor(p, 1);
        p += __shfl_xor(p, 2);
        if (quarter == 0) sP[r][g] = p + geom_b[g];
    }
    __syncthreads();

    // ---- C. W1: e = tid>>3, s = tid&7 ----
    {
        int e = tid >> 3, s = tid & 7;
        if (e < 120 && s < 3) {
            int i0 = e_i[e], j0 = e_j[e];
            float d2 = 0.f;
            #pragma unroll
            for (int m = 0; m < 16; ++m) { float dd = sP[i0][m] - sP[j0][m]; d2 += dd*dd; }
            float mm = sMask[i0]*sMask[j0];
            d2 *= mm*mm;
            float sc = expf(log_sc[s]);
            sW1e[s][e] = expf(-d2/(2.f*sc*sc + 1e-8f)) * mm;
        }
        if (tid < 24) sW1e[tid >> 3][120 + (tid & 7)] = 0.f;
    }
    __syncthreads();

    // ---- D. W2 + mask extension ----
    if (tid < 560) {
        int t = tid;
        int a = t_ij[t], b2 = t_jk[t], c2 = t_ik[t];
        #pragma unroll
        for (int s = 0; s < 3; ++s) sW2e[s][t] = sW1e[s][a]*sW1e[s][b2]*sW1e[s][c2];
    }
    if (tid < 48) sW2e[tid >> 4][560 + (tid & 15)] = sMask[tid & 15];
    __syncthreads();

    // ---- E. waves 0-2: edge O; wave 3: node O; waves 4-7: rsA partials; 8-15 idle ----
    if (w < 3) {
        int s = w;
        f32x4 acc = {0.f, 0.f, 0.f, 0.f};
        __builtin_amdgcn_s_setprio(1);
        for (int kt = 0; kt < 18; ++kt) {
            U4 ub; ub.u4 = ufrag[kt*64 + lane];
            const float4* w4 = (const float4*)&sW2e[s][kt*32 + kq*8];
            float4 wa = w4[0], wb = w4[1];
            U4 av;
            av.us[0] = f2bf(wa.x * bf2f(ub.us[0]));
            av.us[1] = f2bf(wa.y * bf2f(ub.us[1]));
            av.us[2] = f2bf(wa.z * bf2f(ub.us[2]));
            av.us[3] = f2bf(wa.w * bf2f(ub.us[3]));
            av.us[4] = f2bf(wb.x * bf2f(ub.us[4]));
            av.us[5] = f2bf(wb.y * bf2f(ub.us[5]));
            av.us[6] = f2bf(wb.z * bf2f(ub.us[6]));
            av.us[7] = f2bf(wb.w * bf2f(ub.us[7]));
            acc = __builtin_amdgcn_mfma_f32_16x16x32_bf16(av.bv, ub.bv, acc, 0, 0, 0);
        }
        __builtin_amdgcn_s_setprio(0);
        #pragma unroll
        for (int e = 0; e < 4; ++e) {
            int row = kq*4 + e;
            sO[(3+s)*256 + row*16 + rr] = acc[e] + TAUF*C1[row*16 + rr];
        }
    } else if (w == 3) {
        f32x4 acc3[3];
        acc3[0] = 0.f; acc3[1] = 0.f; acc3[2] = 0.f;
        __builtin_amdgcn_s_setprio(1);
        for (int kt = 0; kt < 4; ++kt) {
            U4 ub; ub.u4 = b1frag[kt*64 + lane];
            float uf[8];
            #pragma unroll
            for (int j = 0; j < 8; ++j) uf[j] = bf2f(ub.us[j]);
            #pragma unroll
            for (int s = 0; s < 3; ++s) {
                const float4* w4 = (const float4*)&sW1e[s][kt*32 + kq*8];
                float4 wa = w4[0], wb = w4[1];
                U4 av;
                av.us[0] = f2bf(wa.x * uf[0]);
                av.us[1] = f2bf(wa.y * uf[1]);
                av.us[2] = f2bf(wa.z * uf[2]);
                av.us[3] = f2bf(wa.w * uf[3]);
                av.us[4] = f2bf(wb.x * uf[4]);
                av.us[5] = f2bf(wb.y * uf[5]);
                av.us[6] = f2bf(wb.z * uf[6]);
                av.us[7] = f2bf(wb.w * uf[7]);
                acc3[s] = __builtin_amdgcn_mfma_f32_16x16x32_bf16(av.bv, ub.bv, acc3[s], 0, 0, 0);
            }
        }
        __builtin_amdgcn_s_setprio(0);
        #pragma unroll
        for (int s = 0; s < 3; ++s)
            #pragma unroll
            for (int e = 0; e < 4; ++e) {
                int row = kq*4 + e;
                sO[s*256 + row*16 + rr] = acc3[s][e] + ((row == rr) ? TAUF : 0.f);
            }
    } else if (w < 8) {
        int idx = tid - 256;
        if (idx < 240) {
            int s = idx / 80, rem = idx % 80;
            int k = rem / 5, ch = rem % 5;
            float p = 0.f;
            int t0 = ch * 112;
            for (int i = 0; i < 112; ++i) {
                int t = t0 + i;
                p += sW2e[s][t] * sSig[t] * Up[k*560 + t];
            }
            sRs[(s*16 + k)*5 + ch] = p;
        }
    }
    __syncthreads();

    if (tid < 48) {
        int k = tid & 15;
        float a = TAUF * r2[k];
        #pragma unroll
        for (int p = 0; p < 16; ++p) a += C0[k*16 + p] * sMask[p] * r1[p];
        #pragma unroll
        for (int ch = 0; ch < 5; ++ch) a += sRs[tid*5 + ch];
        sRsA[tid] = a;
    }

    // ---- F. blk-wise Y-GEMM + O-contraction; dbuf sYb, ONE barrier per blk ----
    {
        const int o = tid & 255, kh = tid >> 8;    // kh: 4 row-quads
        float accX[4] = {0.f, 0.f, 0.f, 0.f};
        float xr[4];
        #pragma unroll
        for (int i = 0; i < 4; ++i)
            xr[i] = x[((size_t)bb*16 + kh*4 + i)*256 + o];
        U4 qf[8];
        #pragma unroll
        for (int kt = 0; kt < 8; ++kt)
            qf[kt].u4 = *(const uint4*)(Qt + ((size_t)(0*256 + w*16 + rr))*256 + kt*32 + kq*8);
        for (int blk = 0; blk < 6; ++blk) {
            f32x4 ya = {0.f, 0.f, 0.f, 0.f};
            __builtin_amdgcn_s_setprio(1);
            #pragma unroll
            for (int kt = 0; kt < 8; ++kt) {
                int kg = kt*4 + kq;
                int swz = (kg & 24) | ((kg & 7) ^ (rr & 7));
                bf16x8 af = *(const bf16x8*)&sNB[rr*256 + swz*8];
                ya = __builtin_amdgcn_mfma_f32_16x16x32_bf16(af, qf[kt].bv, ya, 0, 0, 0);
            }
            __builtin_amdgcn_s_setprio(0);
            if (blk < 5) {
                #pragma unroll
                for (int kt = 0; kt < 8; ++kt)
                    qf[kt].u4 = *(const uint4*)(Qt + ((size_t)((blk+1)*256 + w*16 + rr))*256 + kt*32 + kq*8);
            }
            const int buf = blk & 1;
            #pragma unroll
            for (int e = 0; e < 4; ++e) {
                int l = kq*4 + e;
                sYb[buf][l*264 + w*16 + rr] = f2bf(ya[e]);
            }
            __syncthreads();          // writes of buf visible; prior reads of buf (blk-2) drained
            #pragma unroll
            for (int l = 0; l < 16; ++l) {
                float y = bf2f(sYb[buf][l*264 + o]);
                #pragma unroll
                for (int i = 0; i < 4; ++i)
                    accX[i] += sO[blk*256 + (kh*4 + i)*16 + l] * y;
            }
        }
        float b0v = bias0[o], c0v = ce[o], c1v = ce[256+o], c2v = ce[512+o];
        #pragma unroll
        for (int i = 0; i < 4; ++i) {
            int k = kh*4 + i;
            float v = accX[i] + b0v
                    + sRsA[     k] * c0v
                    + sRsA[16 + k] * c1v
                    + sRsA[32 + k] * c2v
                    + xr[i];
            sFbuf[k][o] = v;                       // x2 (xn dead)
        }
    }
    __syncthreads();

    // ---- G. LN2 -> sNB (x2n bf16 chunks) ----
    {
        const int r = w, q = lane;
        float v[4];
        v[0] = sFbuf[r][q*4+0]; v[1] = sFbuf[r][q*4+1];
        v[2] = sFbuf[r][q*4+2]; v[3] = sFbuf[r][q*4+3];
        float sum = v[0]+v[1]+v[2]+v[3];
        float ss  = v[0]*v[0]+v[1]*v[1]+v[2]*v[2]+v[3]*v[3];
        #pragma unroll
        for (int o = 32; o; o >>= 1) { sum += __shfl_xor(sum, o); ss += __shfl_xor(ss, o); }
        float mean = sum * (1.f/256.f);
        float rstd = rsqrtf(ss*(1.f/256.f) - mean*mean + LNEPS);
        ushort4 pk;
        pk.x = f2bf((v[0]-mean)*rstd*n2g[q*4+0] + n2b[q*4+0]);
        pk.y = f2bf((v[1]-mean)*rstd*n2g[q*4+1] + n2b[q*4+1]);
        pk.z = f2bf((v[2]-mean)*rstd*n2g[q*4+2] + n2b[q*4+2]);
        pk.w = f2bf((v[3]-mean)*rstd*n2g[q*4+3] + n2b[q*4+3]);
        int kg = q >> 1;
        int swz = (kg & 24) | ((kg & 7) ^ (r & 7));
        *(ushort4*)&sNB[r*256 + swz*8 + (q & 1)*4] = pk;
    }
    __syncthreads();

    // ---- H. FFN1: wave w -> 4 n-tiles; h -> sH (frag layout) ----
    {
        U4 wb[8];
        #pragma unroll
        for (int kt = 0; kt < 8; ++kt)
            wb[kt].u4 = *(const uint4*)(w1t + (size_t)((w*4+0)*16 + rr)*256 + kt*32 + kq*8);
        #pragma unroll
        for (int j = 0; j < 4; ++j) {
            int nt = w*4 + j;
            f32x4 acc = {0.f, 0.f, 0.f, 0.f};
            __builtin_amdgcn_s_setprio(1);
            #pragma unroll
            for (int kt = 0; kt < 8; ++kt) {
                int kg = kt*4 + kq;
                int swz = (kg & 24) | ((kg & 7) ^ (rr & 7));
                bf16x8 af = *(const bf16x8*)&sNB[rr*256 + swz*8];
                acc = __builtin_amdgcn_mfma_f32_16x16x32_bf16(af, wb[kt].bv, acc, 0, 0, 0);
            }
            __builtin_amdgcn_s_setprio(0);
            if (j < 3) {
                #pragma unroll
                for (int kt = 0; kt < 8; ++kt)
                    wb[kt].u4 = *(const uint4*)(w1t + (size_t)((nt+1)*16 + rr)*256 + kt*32 + kq*8);
            }
            int n = nt*16 + rr;
            float bias = f1b[n];
            int hkg = n >> 3, hlo = n & 7;
            #pragma unroll
            for (int e = 0; e < 4; ++e) {
                int m = kq*4 + e;
                float v = acc[e] + bias;
                v = 0.5f * v * (1.f + erff(v * 0.70710678118654752f));
                int hswz = (hkg & 120) | ((hkg & 7) ^ (m & 7));
                sH[m*1024 + hswz*8 + hlo] = f2bf(v);
            }
        }
    }
    __syncthreads();

    // ---- I. FFN2: wave w -> 1 n-tile; out = x2 + h @ w2t^T + b2 ----
    {
        U4 qb[8];
        #pragma unroll
        for (int kt = 0; kt < 8; ++kt)
            qb[kt].u4 = *(const uint4*)(w2t + (size_t)(w*16 + rr)*1024 + kt*32 + kq*8);
        f32x4 acc = {0.f, 0.f, 0.f, 0.f};
        #pragma unroll
        for (int grp = 0; grp < 4; ++grp) {
            __builtin_amdgcn_s_setprio(1);
            #pragma unroll
            for (int kt = 0; kt < 8; ++kt) {
                int hkg = (grp*8 + kt)*4 + kq;
                int hswz = (hkg & 120) | ((hkg & 7) ^ (rr & 7));
                bf16x8 af = *(const bf16x8*)&sH[rr*1024 + hswz*8];
                acc = __builtin_amdgcn_mfma_f32_16x16x32_bf16(af, qb[kt].bv, acc, 0, 0, 0);
            }
            __builtin_amdgcn_s_setprio(0);
            if (grp < 3) {
                #pragma unroll
                for (int kt = 0; kt < 8; ++kt)
                    qb[kt].u4 = *(const uint4*)(w2t + (size_t)(w*16 + rr)*1024 + ((grp+1)*8 + kt)*32 + kq*8);
            }
        }
        int col = w*16 + rr;
        float bias = f2b[col];
        #pragma unroll
        for (int e = 0; e < 4; ++e) {
            int row = kq*4 + e;
            outp[((size_t)bb*16 + row)*256 + col] = acc[e] + bias + sFbuf[row][col];
        }
    }
}

extern "C" void kernel_launch(void* const* d_in, const int* in_sizes, int n_in,
                              void* d_out, int out_size, void* d_ws, size_t ws_size,
                              hipStream_t stream)
{
    (void)in_sizes; (void)n_in; (void)out_size;
    const float* x      = (const float*)d_in[0];
    const float* mask   = (const float*)d_in[1];
    const float* B1g    = (const float*)d_in[2];
    const float* B2g    = (const float*)d_in[3];
    const float* absB1  = (const float*)d_in[4];
    const int*   e_i    = (const int*)d_in[5];
    const int*   e_j    = (const int*)d_in[6];
    const int*   t_ij   = (const int*)d_in[7];
    const int*   t_jk   = (const int*)d_in[8];
    const int*   t_ik   = (const int*)d_in[9];
    const float* geom_w = (const float*)d_in[10];
    const float* geom_b = (const float*)d_in[11];
    const float* log_sc = (const float*)d_in[12];
    const float* wv0_w  = (const float*)d_in[13];
    const float* wv0_b  = (const float*)d_in[14];
    const float* wein_w = (const float*)d_in[15];
    const float* wein_b = (const float*)d_in[16];
    const float* out_w  = (const float*)d_in[17];
    const float* out_b  = (const float*)d_in[18];
    const float* n1_g   = (const float*)d_in[19];
    const float* n1_b   = (const float*)d_in[20];
    const float* n2_g   = (const float*)d_in[21];
    const float* n2_b   = (const float*)d_in[22];
    const float* ffn1_w = (const float*)d_in[23];
    const float* ffn1_b = (const float*)d_in[24];
    const float* ffn2_w = (const float*)d_in[25];
    const float* ffn2_b = (const float*)d_in[26];

    float* out = (float*)d_out;
    float* ws  = (float*)d_ws;
    if (ws_size < (size_t)WS_FLOATS * sizeof(float)) return;

    float* ce    = ws + CE_OFF;
    float* bias0 = ws + B0_OFF;
    float* C0    = ws + C0_OFF;
    float* C1    = ws + C1_OFF;
    float* U     = ws + U_OFF;
    float* sg    = ws + SG_OFF;
    float* r1    = ws + R1_OFF;
    float* r2    = ws + R2_OFF;
    uint4* ufrag  = (uint4*)(ws + UF_OFF);
    uint4* b1frag = (uint4*)(ws + B1F_OFF);
    unsigned short* Qt  = (unsigned short*)(ws + QT_OFF);
    unsigned short* w1t = (unsigned short*)(ws + W1T_OFF);
    unsigned short* w2t = (unsigned short*)(ws + W2T_OFF);

    prep_k<<<670, 256, 0, stream>>>(wv0_w, wein_w, out_w, ffn1_w, ffn2_w,
                                    wv0_b, wein_b, out_b, B1g, absB1, B2g,
                                    Qt, w1t, w2t,
                                    ce, bias0, C0, C1, U, sg, r1, r2,
                                    ufrag, b1frag);
    k_mega<<<256, 1024, 0, stream>>>(x, mask, e_i, e_j, t_ij, t_jk, t_ik,
                                     geom_w, geom_b, log_sc, n1_g, n1_b, n2_g, n2_b,
                                     C0, C1, U, sg, r1, r2, ufrag, b1frag,
                                     Qt, bias0, ce,
                                     w1t, ffn1_b, w2t, ffn2_b, out);
}

// Round 11
// 99.837 us; speedup vs baseline: 1.1466x; 1.0263x over previous
//
#include <hip/hip_runtime.h>
#include <math.h>

#define TAUF  1.0e-4f
#define LNEPS 1.0e-5f

typedef __bf16 bf16x8 __attribute__((ext_vector_type(8)));
typedef float  f32x4  __attribute__((ext_vector_type(4)));

union U4 { uint4 u4; unsigned short us[8]; bf16x8 bv; };

static __device__ __forceinline__ unsigned short f2bf(float f) {
    union { float f; unsigned u; } v; v.f = f;
    unsigned r = v.u + 0x7fffu + ((v.u >> 16) & 1u);
    return (unsigned short)(r >> 16);
}
static __device__ __forceinline__ float bf2f(unsigned short h) {
    union { unsigned u; float f; } v; v.u = ((unsigned)h) << 16;
    return v.f;
}

// ---------------- workspace layout (float offsets, all 16B-aligned) ----------------
static const unsigned CE_OFF   = 0u;         // 768
static const unsigned B0_OFF   = 768u;       // 256
static const unsigned C1_OFF   = 1024u;      // 256
static const unsigned R2_OFF   = 1280u;      // 16
static const unsigned UF_OFF   = 1296u;      // 18*64 uint4 = 4608 f
static const unsigned B1F_OFF  = 5904u;      // 4*64 uint4  = 1024 f
static const unsigned GF_OFF   = 6928u;      // 18*64 uint4 = 4608 f
static const unsigned QT_OFF   = 11536u;     // 393216 bf16 = 196608 f
static const unsigned W1T_OFF  = 208144u;    // 262144 bf16 = 131072 f
static const unsigned W2T_OFF  = 339216u;    // 262144 bf16 = 131072 f
static const unsigned WS_FLOATS = 470288u;   // ~1.9 MB

// ================= prep: ALL x-independent prep in ONE launch =================
// b <  96 : Qt MFMA GEMM (2-stage LDS, 3 barriers)
// b < 352 : transpose ffn1_w -> w1t bf16
// b < 608 : transpose ffn2_w -> w2t bf16
// b < 612 : bias folds (ce, bias0) -- LDS-staged streaming
// b = 612 : complex constants (C1, r2)
// b < 631 : ufrag (18, parallelized) ; b < 635 : b1frag (4) ; b < 653 : gfrag (18, parallelized)
__launch_bounds__(256, 2)
__global__ void prep_k(const float* __restrict__ wv0_w, const float* __restrict__ wein_w,
                       const float* __restrict__ out_w,
                       const float* __restrict__ ffn1_w, const float* __restrict__ ffn2_w,
                       const float* __restrict__ wv0_b, const float* __restrict__ wein_b,
                       const float* __restrict__ out_b,
                       const float* __restrict__ B1g, const float* __restrict__ absB1,
                       const float* __restrict__ B2g,
                       unsigned short* __restrict__ Qt,
                       unsigned short* __restrict__ w1t, unsigned short* __restrict__ w2t,
                       float* __restrict__ ce, float* __restrict__ bias0,
                       float* __restrict__ C1, float* __restrict__ r2,
                       uint4* __restrict__ ufrag, uint4* __restrict__ b1frag,
                       uint4* __restrict__ gfrag)
{
    __shared__ float tile[32][33];
    __shared__ float sTf[128][68];
    __shared__ float sW[32][257];
    __shared__ unsigned short sFrag[64][8];
    int b = blockIdx.x, tid = threadIdx.x;
    if (b < 96) {
        int by = b >> 2, bx = b & 3;
        int row0 = by * 64, col0 = bx * 64;
        int z = row0 >> 8, o0 = row0 & 255;
        int s = (z < 3) ? z : z - 3;
        const float* Wsel = (z < 3) ? wv0_w : wein_w;
        int lane = tid & 63, w = tid >> 6;
        int rr = lane & 15, kq = lane >> 4;
        f32x4 acc[4];
        #pragma unroll
        for (int cg = 0; cg < 4; ++cg) acc[cg] = 0.f;
        for (int st = 0; st < 2; ++st) {
            #pragma unroll
            for (int i = 0; i < 8; ++i) {
                int idx = i*256 + tid;
                int dd = idx >> 4, q = idx & 15;
                float4 v = *(const float4*)(out_w + (size_t)(z*256 + st*128 + dd)*256 + o0 + q*4);
                *(float4*)&sTf[dd][q*4] = v;
            }
            __syncthreads();
            for (int ks2 = 0; ks2 < 4; ++ks2) {
                int ks = st*4 + ks2;
                U4 av;
                #pragma unroll
                for (int j = 0; j < 8; ++j)
                    av.us[j] = f2bf(sTf[ks2*32 + kq*8 + j][w*16 + rr]);
                #pragma unroll
                for (int cg = 0; cg < 4; ++cg) {
                    const float* bp = Wsel + (size_t)(col0 + cg*16 + rr)*768 + s*256 + ks*32 + kq*8;
                    float4 b0 = *(const float4*)bp, b1 = *(const float4*)(bp + 4);
                    U4 bv;
                    bv.us[0]=f2bf(b0.x); bv.us[1]=f2bf(b0.y); bv.us[2]=f2bf(b0.z); bv.us[3]=f2bf(b0.w);
                    bv.us[4]=f2bf(b1.x); bv.us[5]=f2bf(b1.y); bv.us[6]=f2bf(b1.z); bv.us[7]=f2bf(b1.w);
                    acc[cg] = __builtin_amdgcn_mfma_f32_16x16x32_bf16(av.bv, bv.bv, acc[cg], 0, 0, 0);
                }
            }
            __syncthreads();
        }
        #pragma unroll
        for (int cg = 0; cg < 4; ++cg)
            #pragma unroll
            for (int e = 0; e < 4; ++e) {
                int row = row0 + w*16 + kq*4 + e;
                int col = col0 + cg*16 + rr;
                Qt[(size_t)row*256 + col] = f2bf(acc[cg][e]);
            }
    } else if (b < 352) {
        int bi = b - 96;
        int c0 = (bi & 31) * 32, r0 = (bi >> 5) * 32;
        int tx = tid & 31, ty = tid >> 5;
        #pragma unroll
        for (int i = 0; i < 4; ++i)
            tile[ty + i*8][tx] = ffn1_w[(size_t)(r0 + ty + i*8)*1024 + c0 + tx];
        __syncthreads();
        #pragma unroll
        for (int i = 0; i < 4; ++i)
            w1t[(size_t)(c0 + ty + i*8)*256 + r0 + tx] = f2bf(tile[tx][ty + i*8]);
    } else if (b < 608) {
        int bi = b - 352;
        int c0 = (bi & 7) * 32, r0 = (bi >> 3) * 32;
        int tx = tid & 31, ty = tid >> 5;
        #pragma unroll
        for (int i = 0; i < 4; ++i)
            tile[ty + i*8][tx] = ffn2_w[(size_t)(r0 + ty + i*8)*256 + c0 + tx];
        __syncthreads();
        #pragma unroll
        for (int i = 0; i < 4; ++i)
            w2t[(size_t)(c0 + ty + i*8)*1024 + r0 + tx] = f2bf(tile[tx][ty + i*8]);
    } else if (b < 612) {
        int which = b - 608;
        int o = tid;
        float acc = 0.f;
        if (which == 3) {
            for (int rc = 0; rc < 768; rc += 32) {
                #pragma unroll
                for (int i = 0; i < 32; ++i) sW[i][tid] = out_w[(size_t)(rc+i)*256 + tid];
                __syncthreads();
                #pragma unroll
                for (int i = 0; i < 32; ++i) acc += wv0_b[rc+i] * sW[i][tid];
                __syncthreads();
            }
            bias0[o] = out_b[o] + TAUF * acc;
        } else {
            int base = 768 + which*256;
            for (int rc = 0; rc < 256; rc += 32) {
                #pragma unroll
                for (int i = 0; i < 32; ++i) sW[i][tid] = out_w[(size_t)(base+rc+i)*256 + tid];
                __syncthreads();
                #pragma unroll
                for (int i = 0; i < 32; ++i) acc += wein_b[which*256 + rc+i] * sW[i][tid];
                __syncthreads();
            }
            ce[which*256 + o] = acc;
        }
    } else if (b == 612) {
        int p = tid >> 4, q = tid & 15;
        float c1 = 0.f;
        for (int e = 0; e < 120; ++e) c1 += absB1[p*120+e] * absB1[q*120+e];
        C1[tid] = c1;
        if (tid < 16) {
            float bb = 0.f;
            for (int e = 0; e < 120; ++e) bb += absB1[tid*120+e];
            r2[tid] = bb;
        }
    } else if (b < 631) {
        // ufrag kt = b-613, parallelized: 512 items over 256 threads
        int kt = b - 613;
        #pragma unroll
        for (int it = 0; it < 2; ++it) {
            int item = it*256 + tid;
            int lane = item >> 3, j = item & 7;
            int col = lane & 15, kq = lane >> 4;
            int t = kt*32 + kq*8 + j;
            float v = 0.f;
            if (t < 560) {
                for (int e = 0; e < 120; ++e) v += absB1[col*120+e] * B2g[e*560+t];
            } else {
                int p = t - 560;
                for (int e = 0; e < 120; ++e) v += absB1[col*120+e] * B1g[p*120+e];
            }
            sFrag[lane][j] = f2bf(v);
        }
        __syncthreads();
        if (tid < 64) {
            U4 o;
            #pragma unroll
            for (int j = 0; j < 8; ++j) o.us[j] = sFrag[tid][j];
            ufrag[kt*64 + tid] = o.u4;
        }
    } else if (b < 635) {
        if (tid < 64) {
            int lane = tid, col = lane & 15, kq = lane >> 4;
            int kt = b - 631;
            U4 o;
            #pragma unroll
            for (int j = 0; j < 8; ++j) {
                int e = kt*32 + kq*8 + j;
                o.us[j] = f2bf((e < 120) ? B1g[col*120 + e] : 0.f);
            }
            b1frag[kt*64 + lane] = o.u4;
        }
    } else {
        // gfrag kt = b-635: sig[t]*U[col][t] (t<560) / C0[col][p]*r1[p] (ext), parallelized
        int kt = b - 635;
        #pragma unroll
        for (int it = 0; it < 2; ++it) {
            int item = it*256 + tid;
            int lane = item >> 3, j = item & 7;
            int col = lane & 15, kq = lane >> 4;
            int t = kt*32 + kq*8 + j;
            float g;
            if (t < 560) {
                float u = 0.f, sgv = 0.f;
                for (int e = 0; e < 120; ++e) {
                    float bv = B2g[e*560+t];
                    u += absB1[col*120+e] * bv;
                    sgv += bv;
                }
                g = sgv * u;
            } else {
                int p = t - 560;
                float c0 = 0.f, r1v = 0.f;
                for (int e = 0; e < 120; ++e) {
                    float bv = B1g[p*120+e];
                    c0 += absB1[col*120+e] * bv;
                    r1v += bv;
                }
                g = c0 * r1v;
            }
            sFrag[lane][j] = f2bf(g);
        }
        __syncthreads();
        if (tid < 64) {
            U4 o;
            #pragma unroll
            for (int j = 0; j < 8; ++j) o.us[j] = sFrag[tid][j];
            gfrag[kt*64 + tid] = o.u4;
        }
    }
}

// ============== k_mega: R10 structure, serial-chain fixes in A/B/E ==============
__launch_bounds__(1024, 4)
__global__ void k_mega(const float* __restrict__ x, const float* __restrict__ mask,
                       const int* __restrict__ e_i, const int* __restrict__ e_j,
                       const int* __restrict__ t_ij, const int* __restrict__ t_jk,
                       const int* __restrict__ t_ik,
                       const float* __restrict__ geom_w, const float* __restrict__ geom_b,
                       const float* __restrict__ log_sc,
                       const float* __restrict__ n1_g, const float* __restrict__ n1_b,
                       const float* __restrict__ n2g, const float* __restrict__ n2b,
                       const float* __restrict__ C1, const float* __restrict__ r2,
                       const uint4* __restrict__ ufrag, const uint4* __restrict__ b1frag,
                       const uint4* __restrict__ gfrag,
                       const unsigned short* __restrict__ Qt,
                       const float* __restrict__ bias0, const float* __restrict__ ce,
                       const unsigned short* __restrict__ w1t, const float* __restrict__ f1b,
                       const unsigned short* __restrict__ w2t, const float* __restrict__ f2b,
                       float* __restrict__ outp)
{
    __shared__ float sFbuf[16][264];           // xn (phases A-B), then x2 (F-I)
    __shared__ unsigned short sNB[16*256];     // bf16 xn chunks (A-F), then x2n chunks (G-H)
    __shared__ unsigned short sH[16*1024];     // h, frag layout (FFN2 A-frags)
    __shared__ float sGW[4096];                // geom_w staged (16 KB)
    __shared__ float sP[16][17];
    __shared__ float sW1e[3][128];
    __shared__ float sW2e[3][576];
    __shared__ float sMask[16];
    __shared__ float sO[6*256];
    __shared__ float sRsA[48];
    __shared__ unsigned short sYb[2][16*264];  // Y blk tile, double-buffered

    const int bb = blockIdx.x, tid = threadIdx.x;
    const int w = tid >> 6, lane = tid & 63;
    const int rr = lane & 15, kq = lane >> 4;

    // ---- A. LayerNorm 1 (wave w = row w) + stage geom_w into LDS ----
    {
        const int r = w, q = lane;
        const float* row = x + ((size_t)bb*16 + r)*256 + q*4;
        float4 va = *(const float4*)row;
        *(float4*)&sGW[tid*4] = *(const float4*)(geom_w + tid*4);   // 4096 floats, coalesced
        float v[4] = {va.x, va.y, va.z, va.w};
        float sum = v[0]+v[1]+v[2]+v[3];
        float ss  = v[0]*v[0]+v[1]*v[1]+v[2]*v[2]+v[3]*v[3];
        #pragma unroll
        for (int o = 32; o; o >>= 1) { sum += __shfl_xor(sum, o); ss += __shfl_xor(ss, o); }
        float mean = sum * (1.f/256.f);
        float rstd = rsqrtf(ss*(1.f/256.f) - mean*mean + LNEPS);
        ushort4 pk;
        float xv0 = (v[0]-mean)*rstd*n1_g[q*4+0] + n1_b[q*4+0];
        float xv1 = (v[1]-mean)*rstd*n1_g[q*4+1] + n1_b[q*4+1];
        float xv2 = (v[2]-mean)*rstd*n1_g[q*4+2] + n1_b[q*4+2];
        float xv3 = (v[3]-mean)*rstd*n1_g[q*4+3] + n1_b[q*4+3];
        sFbuf[r][q*4+0] = xv0; sFbuf[r][q*4+1] = xv1;
        sFbuf[r][q*4+2] = xv2; sFbuf[r][q*4+3] = xv3;
        pk.x = f2bf(xv0); pk.y = f2bf(xv1); pk.z = f2bf(xv2); pk.w = f2bf(xv3);
        int kg = q >> 1;
        int swz = (kg & 24) | ((kg & 7) ^ (r & 7));
        *(ushort4*)&sNB[r*256 + swz*8 + (q & 1)*4] = pk;
        if (tid < 16) sMask[tid] = mask[bb*16 + tid];
    }
    __syncthreads();

    // ---- B. P = xn @ geom_w + geom_b: fully unrolled over LDS ----
    {
        const int r = w, g = (lane >> 2) & 15, quarter = lane & 3;
        const int cb = quarter * 64;
        float a0 = 0.f, a1 = 0.f, a2 = 0.f, a3 = 0.f;
        #pragma unroll
        for (int c = 0; c < 64; c += 4) {
            float4 xv = *(const float4*)&sFbuf[r][cb + c];
            a0 += xv.x * sGW[(cb+c+0)*16 + g];
            a1 += xv.y * sGW[(cb+c+1)*16 + g];
            a2 += xv.z * sGW[(cb+c+2)*16 + g];
            a3 += xv.w * sGW[(cb+c+3)*16 + g];
        }
        float p = (a0+a1) + (a2+a3);
        p += __shfl_xor(p, 1);
        p += __shfl_xor(p, 2);
        if (quarter == 0) sP[r][g] = p + geom_b[g];
    }
    __syncthreads();

    // ---- C. W1: e = tid>>3, s = tid&7 ----
    {
        int e = tid >> 3, s = tid & 7;
        if (e < 120 && s < 3) {
            int i0 = e_i[e], j0 = e_j[e];
            float d2 = 0.f;
            #pragma unroll
            for (int m = 0; m < 16; ++m) { float dd = sP[i0][m] - sP[j0][m]; d2 += dd*dd; }
            float mm = sMask[i0]*sMask[j0];
            d2 *= mm*mm;
            float sc = expf(log_sc[s]);
            sW1e[s][e] = expf(-d2/(2.f*sc*sc + 1e-8f)) * mm;
        }
        if (tid < 24) sW1e[tid >> 3][120 + (tid & 7)] = 0.f;
    }
    __syncthreads();

    // ---- D. W2 + mask extension ----
    if (tid < 560) {
        int t = tid;
        int a = t_ij[t], b2 = t_jk[t], c2 = t_ik[t];
        #pragma unroll
        for (int s = 0; s < 3; ++s) sW2e[s][t] = sW1e[s][a]*sW1e[s][b2]*sW1e[s][c2];
    }
    if (tid < 48) sW2e[tid >> 4][560 + (tid & 15)] = sMask[tid & 15];
    __syncthreads();

    // ---- E. waves 0-2: edge O; wave 3: node O; wave 4: rsA via gfrag MFMA ----
    if (w < 3) {
        int s = w;
        f32x4 acc = {0.f, 0.f, 0.f, 0.f};
        __builtin_amdgcn_s_setprio(1);
        #pragma unroll 3
        for (int kt = 0; kt < 18; ++kt) {
            U4 ub; ub.u4 = ufrag[kt*64 + lane];
            const float4* w4 = (const float4*)&sW2e[s][kt*32 + kq*8];
            float4 wa = w4[0], wb = w4[1];
            U4 av;
            av.us[0] = f2bf(wa.x * bf2f(ub.us[0]));
            av.us[1] = f2bf(wa.y * bf2f(ub.us[1]));
            av.us[2] = f2bf(wa.z * bf2f(ub.us[2]));
            av.us[3] = f2bf(wa.w * bf2f(ub.us[3]));
            av.us[4] = f2bf(wb.x * bf2f(ub.us[4]));
            av.us[5] = f2bf(wb.y * bf2f(ub.us[5]));
            av.us[6] = f2bf(wb.z * bf2f(ub.us[6]));
            av.us[7] = f2bf(wb.w * bf2f(ub.us[7]));
            acc = __builtin_amdgcn_mfma_f32_16x16x32_bf16(av.bv, ub.bv, acc, 0, 0, 0);
        }
        __builtin_amdgcn_s_setprio(0);
        #pragma unroll
        for (int e = 0; e < 4; ++e) {
            int row = kq*4 + e;
            sO[(3+s)*256 + row*16 + rr] = acc[e] + TAUF*C1[row*16 + rr];
        }
    } else if (w == 3) {
        f32x4 acc3[3];
        acc3[0] = 0.f; acc3[1] = 0.f; acc3[2] = 0.f;
        __builtin_amdgcn_s_setprio(1);
        #pragma unroll
        for (int kt = 0; kt < 4; ++kt) {
            U4 ub; ub.u4 = b1frag[kt*64 + lane];
            float uf[8];
            #pragma unroll
            for (int j = 0; j < 8; ++j) uf[j] = bf2f(ub.us[j]);
            #pragma unroll
            for (int s = 0; s < 3; ++s) {
                const float4* w4 = (const float4*)&sW1e[s][kt*32 + kq*8];
                float4 wa = w4[0], wb = w4[1];
                U4 av;
                av.us[0] = f2bf(wa.x * uf[0]);
                av.us[1] = f2bf(wa.y * uf[1]);
                av.us[2] = f2bf(wa.z * uf[2]);
                av.us[3] = f2bf(wa.w * uf[3]);
                av.us[4] = f2bf(wb.x * uf[4]);
                av.us[5] = f2bf(wb.y * uf[5]);
                av.us[6] = f2bf(wb.z * uf[6]);
                av.us[7] = f2bf(wb.w * uf[7]);
                acc3[s] = __builtin_amdgcn_mfma_f32_16x16x32_bf16(av.bv, ub.bv, acc3[s], 0, 0, 0);
            }
        }
        __builtin_amdgcn_s_setprio(0);
        #pragma unroll
        for (int s = 0; s < 3; ++s)
            #pragma unroll
            for (int e = 0; e < 4; ++e) {
                int row = kq*4 + e;
                sO[s*256 + row*16 + rr] = acc3[s][e] + ((row == rr) ? TAUF : 0.f);
            }
    } else if (w == 4) {
        // rsA[s][k] = TAU*r2[k] + sum_t' W2e[s][t'] * gfrag[k][t']   (18-MFMA chain)
        f32x4 acc = {0.f, 0.f, 0.f, 0.f};
        int srow = (rr < 3) ? rr : 0;
        __builtin_amdgcn_s_setprio(1);
        #pragma unroll 3
        for (int kt = 0; kt < 18; ++kt) {
            U4 gb; gb.u4 = gfrag[kt*64 + lane];
            const float4* w4 = (const float4*)&sW2e[srow][kt*32 + kq*8];
            float4 wa = w4[0], wb = w4[1];
            U4 av;
            av.us[0] = f2bf(wa.x); av.us[1] = f2bf(wa.y);
            av.us[2] = f2bf(wa.z); av.us[3] = f2bf(wa.w);
            av.us[4] = f2bf(wb.x); av.us[5] = f2bf(wb.y);
            av.us[6] = f2bf(wb.z); av.us[7] = f2bf(wb.w);
            acc = __builtin_amdgcn_mfma_f32_16x16x32_bf16(av.bv, gb.bv, acc, 0, 0, 0);
        }
        __builtin_amdgcn_s_setprio(0);
        if (kq == 0) {
            #pragma unroll
            for (int e = 0; e < 3; ++e)
                sRsA[e*16 + rr] = acc[e] + TAUF * r2[rr];
        }
    }
    __syncthreads();

    // ---- F. blk-wise Y-GEMM + O-contraction; dbuf sYb, one barrier per blk ----
    {
        const int o = tid & 255, kh = tid >> 8;
        float accX[4] = {0.f, 0.f, 0.f, 0.f};
        float xr[4];
        #pragma unroll
        for (int i = 0; i < 4; ++i)
            xr[i] = x[((size_t)bb*16 + kh*4 + i)*256 + o];
        U4 qf[8];
        #pragma unroll
        for (int kt = 0; kt < 8; ++kt)
            qf[kt].u4 = *(const uint4*)(Qt + ((size_t)(0*256 + w*16 + rr))*256 + kt*32 + kq*8);
        for (int blk = 0; blk < 6; ++blk) {
            f32x4 ya = {0.f, 0.f, 0.f, 0.f};
            __builtin_amdgcn_s_setprio(1);
            #pragma unroll
            for (int kt = 0; kt < 8; ++kt) {
                int kg = kt*4 + kq;
                int swz = (kg & 24) | ((kg & 7) ^ (rr & 7));
                bf16x8 af = *(const bf16x8*)&sNB[rr*256 + swz*8];
                ya = __builtin_amdgcn_mfma_f32_16x16x32_bf16(af, qf[kt].bv, ya, 0, 0, 0);
            }
            __builtin_amdgcn_s_setprio(0);
            if (blk < 5) {
                #pragma unroll
                for (int kt = 0; kt < 8; ++kt)
                    qf[kt].u4 = *(const uint4*)(Qt + ((size_t)((blk+1)*256 + w*16 + rr))*256 + kt*32 + kq*8);
            }
            const int buf = blk & 1;
            #pragma unroll
            for (int e = 0; e < 4; ++e) {
                int l = kq*4 + e;
                sYb[buf][l*264 + w*16 + rr] = f2bf(ya[e]);
            }
            __syncthreads();
            #pragma unroll
            for (int l = 0; l < 16; ++l) {
                float y = bf2f(sYb[buf][l*264 + o]);
                #pragma unroll
                for (int i = 0; i < 4; ++i)
                    accX[i] += sO[blk*256 + (kh*4 + i)*16 + l] * y;
            }
        }
        float b0v = bias0[o], c0v = ce[o], c1v = ce[256+o], c2v = ce[512+o];
        #pragma unroll
        for (int i = 0; i < 4; ++i) {
            int k = kh*4 + i;
            float v = accX[i] + b0v
                    + sRsA[     k] * c0v
                    + sRsA[16 + k] * c1v
                    + sRsA[32 + k] * c2v
                    + xr[i];
            sFbuf[k][o] = v;
        }
    }
    __syncthreads();

    // ---- G. LN2 -> sNB (x2n bf16 chunks) ----
    {
        const int r = w, q = lane;
        float v[4];
        v[0] = sFbuf[r][q*4+0]; v[1] = sFbuf[r][q*4+1];
        v[2] = sFbuf[r][q*4+2]; v[3] = sFbuf[r][q*4+3];
        float sum = v[0]+v[1]+v[2]+v[3];
        float ss  = v[0]*v[0]+v[1]*v[1]+v[2]*v[2]+v[3]*v[3];
        #pragma unroll
        for (int o = 32; o; o >>= 1) { sum += __shfl_xor(sum, o); ss += __shfl_xor(ss, o); }
        float mean = sum * (1.f/256.f);
        float rstd = rsqrtf(ss*(1.f/256.f) - mean*mean + LNEPS);
        ushort4 pk;
        pk.x = f2bf((v[0]-mean)*rstd*n2g[q*4+0] + n2b[q*4+0]);
        pk.y = f2bf((v[1]-mean)*rstd*n2g[q*4+1] + n2b[q*4+1]);
        pk.z = f2bf((v[2]-mean)*rstd*n2g[q*4+2] + n2b[q*4+2]);
        pk.w = f2bf((v[3]-mean)*rstd*n2g[q*4+3] + n2b[q*4+3]);
        int kg = q >> 1;
        int swz = (kg & 24) | ((kg & 7) ^ (r & 7));
        *(ushort4*)&sNB[r*256 + swz*8 + (q & 1)*4] = pk;
    }
    __syncthreads();

    // ---- H. FFN1: wave w -> 4 n-tiles; h -> sH (frag layout) ----
    {
        U4 wb[8];
        #pragma unroll
        for (int kt = 0; kt < 8; ++kt)
            wb[kt].u4 = *(const uint4*)(w1t + (size_t)((w*4+0)*16 + rr)*256 + kt*32 + kq*8);
        #pragma unroll
        for (int j = 0; j < 4; ++j) {
            int nt = w*4 + j;
            f32x4 acc = {0.f, 0.f, 0.f, 0.f};
            __builtin_amdgcn_s_setprio(1);
            #pragma unroll
            for (int kt = 0; kt < 8; ++kt) {
                int kg = kt*4 + kq;
                int swz = (kg & 24) | ((kg & 7) ^ (rr & 7));
                bf16x8 af = *(const bf16x8*)&sNB[rr*256 + swz*8];
                acc = __builtin_amdgcn_mfma_f32_16x16x32_bf16(af, wb[kt].bv, acc, 0, 0, 0);
            }
            __builtin_amdgcn_s_setprio(0);
            if (j < 3) {
                #pragma unroll
                for (int kt = 0; kt < 8; ++kt)
                    wb[kt].u4 = *(const uint4*)(w1t + (size_t)((nt+1)*16 + rr)*256 + kt*32 + kq*8);
            }
            int n = nt*16 + rr;
            float bias = f1b[n];
            int hkg = n >> 3, hlo = n & 7;
            #pragma unroll
            for (int e = 0; e < 4; ++e) {
                int m = kq*4 + e;
                float v = acc[e] + bias;
                v = 0.5f * v * (1.f + erff(v * 0.70710678118654752f));
                int hswz = (hkg & 120) | ((hkg & 7) ^ (m & 7));
                sH[m*1024 + hswz*8 + hlo] = f2bf(v);
            }
        }
    }
    __syncthreads();

    // ---- I. FFN2: wave w -> 1 n-tile; out = x2 + h @ w2t^T + b2 ----
    {
        U4 qb[8];
        #pragma unroll
        for (int kt = 0; kt < 8; ++kt)
            qb[kt].u4 = *(const uint4*)(w2t + (size_t)(w*16 + rr)*1024 + kt*32 + kq*8);
        f32x4 acc = {0.f, 0.f, 0.f, 0.f};
        #pragma unroll
        for (int grp = 0; grp < 4; ++grp) {
            __builtin_amdgcn_s_setprio(1);
            #pragma unroll
            for (int kt = 0; kt < 8; ++kt) {
                int hkg = (grp*8 + kt)*4 + kq;
                int hswz = (hkg & 120) | ((hkg & 7) ^ (rr & 7));
                bf16x8 af = *(const bf16x8*)&sH[rr*1024 + hswz*8];
                acc = __builtin_amdgcn_mfma_f32_16x16x32_bf16(af, qb[kt].bv, acc, 0, 0, 0);
            }
            __builtin_amdgcn_s_setprio(0);
            if (grp < 3) {
                #pragma unroll
                for (int kt = 0; kt < 8; ++kt)
                    qb[kt].u4 = *(const uint4*)(w2t + (size_t)(w*16 + rr)*1024 + ((grp+1)*8 + kt)*32 + kq*8);
            }
        }
        int col = w*16 + rr;
        float bias = f2b[col];
        #pragma unroll
        for (int e = 0; e < 4; ++e) {
            int row = kq*4 + e;
            outp[((size_t)bb*16 + row)*256 + col] = acc[e] + bias + sFbuf[row][col];
        }
    }
}

extern "C" void kernel_launch(void* const* d_in, const int* in_sizes, int n_in,
                              void* d_out, int out_size, void* d_ws, size_t ws_size,
                              hipStream_t stream)
{
    (void)in_sizes; (void)n_in; (void)out_size;
    const float* x      = (const float*)d_in[0];
    const float* mask   = (const float*)d_in[1];
    const float* B1g    = (const float*)d_in[2];
    const float* B2g    = (const float*)d_in[3];
    const float* absB1  = (const float*)d_in[4];
    const int*   e_i    = (const int*)d_in[5];
    const int*   e_j    = (const int*)d_in[6];
    const int*   t_ij   = (const int*)d_in[7];
    const int*   t_jk   = (const int*)d_in[8];
    const int*   t_ik   = (const int*)d_in[9];
    const float* geom_w = (const float*)d_in[10];
    const float* geom_b = (const float*)d_in[11];
    const float* log_sc = (const float*)d_in[12];
    const float* wv0_w  = (const float*)d_in[13];
    const float* wv0_b  = (const float*)d_in[14];
    const float* wein_w = (const float*)d_in[15];
    const float* wein_b = (const float*)d_in[16];
    const float* out_w  = (const float*)d_in[17];
    const float* out_b  = (const float*)d_in[18];
    const float* n1_g   = (const float*)d_in[19];
    const float* n1_b   = (const float*)d_in[20];
    const float* n2_g   = (const float*)d_in[21];
    const float* n2_b   = (const float*)d_in[22];
    const float* ffn1_w = (const float*)d_in[23];
    const float* ffn1_b = (const float*)d_in[24];
    const float* ffn2_w = (const float*)d_in[25];
    const float* ffn2_b = (const float*)d_in[26];

    float* out = (float*)d_out;
    float* ws  = (float*)d_ws;
    if (ws_size < (size_t)WS_FLOATS * sizeof(float)) return;

    float* ce    = ws + CE_OFF;
    float* bias0 = ws + B0_OFF;
    float* C1    = ws + C1_OFF;
    float* r2    = ws + R2_OFF;
    uint4* ufrag  = (uint4*)(ws + UF_OFF);
    uint4* b1frag = (uint4*)(ws + B1F_OFF);
    uint4* gfrag  = (uint4*)(ws + GF_OFF);
    unsigned short* Qt  = (unsigned short*)(ws + QT_OFF);
    unsigned short* w1t = (unsigned short*)(ws + W1T_OFF);
    unsigned short* w2t = (unsigned short*)(ws + W2T_OFF);

    prep_k<<<653, 256, 0, stream>>>(wv0_w, wein_w, out_w, ffn1_w, ffn2_w,
                                    wv0_b, wein_b, out_b, B1g, absB1, B2g,
                                    Qt, w1t, w2t,
                                    ce, bias0, C1, r2,
                                    ufrag, b1frag, gfrag);
    k_mega<<<256, 1024, 0, stream>>>(x, mask, e_i, e_j, t_ij, t_jk, t_ik,
                                     geom_w, geom_b, log_sc, n1_g, n1_b, n2_g, n2_b,
                                     C1, r2, ufrag, b1frag, gfrag,
                                     Qt, bias0, ce,
                                     w1t, ffn1_b, w2t, ffn2_b, out);
}